// Round 1
// 1230.349 us; speedup vs baseline: 1.0285x; 1.0285x over previous
//
#include <hip/hip_runtime.h>
#include <cstdint>
#include <cstddef>

typedef __bf16 bf16;
typedef __bf16 bf16x4 __attribute__((ext_vector_type(4)));
typedef __bf16 bf16x8 __attribute__((ext_vector_type(8)));
typedef float  f32x4  __attribute__((ext_vector_type(4)));

#define LDS_CAST(p) ((__attribute__((address_space(3))) void*)(p))
#define GLB_CAST(p) ((const __attribute__((address_space(1))) void*)(p))

__device__ __forceinline__ void glds16(const void* g, void* l) {
  // 16B per lane, LDS dst = wave-uniform base + lane*16
  __builtin_amdgcn_global_load_lds(GLB_CAST(g), LDS_CAST(l), 16, 0, 0);
}

// ---------------------------------------------------------------------------
// Transpose-convert (all 6 layers, grid.z = layer): w fp32 [K,N] -> wt bf16 [N,K]
// ---------------------------------------------------------------------------
__global__ __launch_bounds__(256)
void convT_k(const float* __restrict__ w, bf16* __restrict__ wt, int K, int N)
{
  __shared__ bf16 t[64][72];
  const int tid = threadIdx.x;
  const int k0 = blockIdx.x * 64, n0 = blockIdx.y * 64;
  w  += (size_t)blockIdx.z * K * N;
  wt += (size_t)blockIdx.z * K * N;
  const int r = tid >> 4, c = (tid & 15) * 4;
#pragma unroll
  for (int p = 0; p < 4; ++p) {
    const int k = p * 16 + r;
    f32x4 v = *(const f32x4*)&w[(size_t)(k0 + k) * N + n0 + c];
    bf16x4 b = { (bf16)v[0], (bf16)v[1], (bf16)v[2], (bf16)v[3] };
    *(bf16x4*)&t[k][c] = b;
  }
  __syncthreads();
#pragma unroll
  for (int p = 0; p < 4; ++p) {
    const int n = p * 16 + r;
    bf16x4 b = { t[c + 0][n], t[c + 1][n], t[c + 2][n], t[c + 3][n] };
    *(bf16x4*)&wt[(size_t)(n0 + n) * K + k0 + c] = b;
  }
}

// ---------------------------------------------------------------------------
// GEMM (m97 structure): C = A[M,K] @ Bt[N,K]^T, both bf16 row-major, glds16
// staging. 128x128 tile, BK=32, 4 waves as 2x2 of 64x64.
// EPI 0: store bf16               EPI 2: +bias, exact GELU, store bf16
// ---------------------------------------------------------------------------
template<int EPI>
__global__ __launch_bounds__(256)
void gemm128_k(const bf16* __restrict__ A, const bf16* __restrict__ Bt,
               const float* __restrict__ bias, bf16* __restrict__ outB,
               int M, int N, int K)
{
  __shared__ bf16 As[128 * 32];
  __shared__ bf16 Bs[128 * 32];

  const int tid  = threadIdx.x;
  const int wave = tid >> 6, lane = tid & 63;
  const int row0 = blockIdx.x * 128, col0 = blockIdx.y * 128;
  const int wm = (wave & 1) * 64, wn = (wave >> 1) * 64;

  f32x4 acc[4][4] = {};

  const int sr = wave * 32 + (lane >> 2);  // staging row within tile
  const int sk = (lane & 3) * 8;           // staging k offset

  const int nk = K >> 5;
  for (int kt = 0; kt < nk; ++kt) {
    const int k0 = kt << 5;
    glds16(&A [(size_t)(row0 + sr)      * K + k0 + sk], &As[(wave * 32)      * 32]);
    glds16(&A [(size_t)(row0 + sr + 16) * K + k0 + sk], &As[(wave * 32 + 16) * 32]);
    glds16(&Bt[(size_t)(col0 + sr)      * K + k0 + sk], &Bs[(wave * 32)      * 32]);
    glds16(&Bt[(size_t)(col0 + sr + 16) * K + k0 + sk], &Bs[(wave * 32 + 16) * 32]);
    __syncthreads();

    bf16x8 af[4], bfr[4];
#pragma unroll
    for (int t = 0; t < 4; ++t) {
      af[t]  = *(const bf16x8*)&As[(wm + t * 16 + (lane & 15)) * 32 + (lane >> 4) * 8];
      bfr[t] = *(const bf16x8*)&Bs[(wn + t * 16 + (lane & 15)) * 32 + (lane >> 4) * 8];
    }
#pragma unroll
    for (int i = 0; i < 4; ++i)
#pragma unroll
      for (int j = 0; j < 4; ++j)
        acc[i][j] = __builtin_amdgcn_mfma_f32_16x16x32_bf16(af[i], bfr[j], acc[i][j], 0, 0, 0);
    __syncthreads();
  }

#pragma unroll
  for (int i = 0; i < 4; ++i) {
    const int rb = row0 + wm + i * 16 + (lane >> 4) * 4;
#pragma unroll
    for (int j = 0; j < 4; ++j) {
      const int c = col0 + wn + j * 16 + (lane & 15);
      const float bv = (EPI == 2) ? bias[c] : 0.f;
#pragma unroll
      for (int r = 0; r < 4; ++r) {
        float v = acc[i][j][r] + bv;
        if (EPI == 2) v = 0.5f * v * (1.f + erff(v * 0.70710678118654752f));
        outB[(size_t)(rb + r) * N + c] = (bf16)v;
      }
    }
  }
}

// ---------------------------------------------------------------------------
// N=1024 GEMMs (wout, ff2): barrier-free per-wave split-K.
// 64x64 output tile, 4 waves; wave g owns K-chunk [g*K/4, (g+1)*K/4).
// Each wave: private double-buffered LDS (A,B 64x32 each), glds16 staging,
// counted s_waitcnt vmcnt(8) 2-deep pipeline, NO __syncthreads in K-loop.
// 4x4 accum (0.5 ds_read_b128 per MFMA). LDS XOR-swizzle (both-sides
// involution, rule #21): 16B slot s of row r holds k-block s ^ ((r>>1)&3),
// applied by pre-swizzling the per-lane GLOBAL source (LDS dest stays
// linear for glds16) and by the fragment-read offset. Makes every 8-lane
// group of the b128 frag reads cover all 32 banks.
// Final cross-wave reduce via LDS (stride-68 fp32 pad, 2-way max):
// out = sum(acc_w) + bias + resid (fp32; resid may alias out).
// Grid 32x16 = 512 blocks, 256 thr, 68KB LDS -> 2 blocks/CU, 8 waves/CU.
// ---------------------------------------------------------------------------
__global__ __launch_bounds__(256, 2)
void gemm64s_k(const bf16* __restrict__ A, const bf16* __restrict__ Bt,
               const float* __restrict__ bias, const float* resid,
               float* outF, int M, int N, int K)
{
  union SMem {
    bf16  stage[4][2][2][2048];   // [wave][buf][A=0/B=1][64*32] = 64 KiB
    float red[4][64 * 68];        // 69632 B (padded stride 68)
  };
  __shared__ SMem sm;

  const int tid  = threadIdx.x;
  const int wave = tid >> 6, lane = tid & 63;
  const int row0 = blockIdx.x * 64, col0 = blockIdx.y * 64;
  const int kChunk = K >> 2;
  const int nk = kChunk >> 5;               // 32-wide K-steps per wave

  // staging: 4 glds16 per matrix per 64x32 tile (16 rows x 64B each);
  // per-lane global k-offset pre-swizzled so linear LDS dest ends up swizzled
  const int srow = lane >> 2;                              // row within 16-chunk
  const int ssw  = ((lane & 3) ^ ((lane >> 3) & 3)) << 3;  // swizzled k elems
  const bf16* Ab = A  + (size_t)(row0 + srow) * K + wave * kChunk + ssw;
  const bf16* Bb = Bt + (size_t)(col0 + srow) * K + wave * kChunk + ssw;

  // fragment reads: slot = fq ^ ((row>>1)&3), constant per lane
  const int fr  = lane & 15;
  const int fq8 = (((lane >> 4) ^ ((fr >> 1) & 3))) << 3;

  f32x4 acc[4][4] = {};

#define STAGE(buf, kt)                                                         \
  {                                                                            \
    const int k0_ = (kt) << 5;                                                 \
    bf16* pa_ = sm.stage[wave][buf][0];                                        \
    bf16* pb_ = sm.stage[wave][buf][1];                                        \
    _Pragma("unroll")                                                          \
    for (int c_ = 0; c_ < 4; ++c_) {                                           \
      glds16(Ab + (size_t)c_ * 16 * K + k0_, pa_ + c_ * 512);                  \
      glds16(Bb + (size_t)c_ * 16 * K + k0_, pb_ + c_ * 512);                  \
    }                                                                          \
  }

#define COMPUTE(buf)                                                           \
  {                                                                            \
    const bf16* pa_ = sm.stage[wave][buf][0];                                  \
    const bf16* pb_ = sm.stage[wave][buf][1];                                  \
    bf16x8 af[4], bfr[4];                                                      \
    _Pragma("unroll")                                                          \
    for (int t_ = 0; t_ < 4; ++t_) {                                           \
      af[t_]  = *(const bf16x8*)(pa_ + (t_ * 16 + fr) * 32 + fq8);             \
      bfr[t_] = *(const bf16x8*)(pb_ + (t_ * 16 + fr) * 32 + fq8);             \
    }                                                                          \
    __builtin_amdgcn_s_setprio(1);                                             \
    _Pragma("unroll")                                                          \
    for (int i_ = 0; i_ < 4; ++i_)                                             \
      _Pragma("unroll")                                                        \
      for (int j_ = 0; j_ < 4; ++j_)                                           \
        acc[i_][j_] = __builtin_amdgcn_mfma_f32_16x16x32_bf16(                 \
            af[i_], bfr[j_], acc[i_][j_], 0, 0, 0);                            \
    __builtin_amdgcn_s_setprio(0);                                             \
  }

  STAGE(0, 0);
  for (int kt = 0; kt < nk - 1; ++kt) {
    STAGE((kt + 1) & 1, kt + 1);                       // 16 outstanding
    asm volatile("s_waitcnt vmcnt(8)" ::: "memory");   // oldest 8 = cur tile
    COMPUTE(kt & 1);
  }
  asm volatile("s_waitcnt vmcnt(0)" ::: "memory");
  COMPUTE((nk - 1) & 1);

#undef STAGE
#undef COMPUTE

  // ---- cross-wave reduction (LDS reused; must fence all waves first) ----
  __syncthreads();
#pragma unroll
  for (int i = 0; i < 4; ++i)
#pragma unroll
    for (int j = 0; j < 4; ++j)
#pragma unroll
      for (int r = 0; r < 4; ++r)
        sm.red[wave][(i * 16 + ((lane >> 4) << 2) + r) * 68 + j * 16 + (lane & 15)] =
            acc[i][j][r];
  __syncthreads();

  const int er = tid >> 2;              // row 0..63
  const int ec = (tid & 3) << 2;        // col quarter-base (stride 16 via v)
  const size_t gbase = (size_t)(row0 + er) * N + col0 + ec;
#pragma unroll
  for (int v = 0; v < 4; ++v) {
    const int lo = er * 68 + ec + v * 16;
    f32x4 s0 = *(const f32x4*)&sm.red[0][lo];
    f32x4 s1 = *(const f32x4*)&sm.red[1][lo];
    f32x4 s2 = *(const f32x4*)&sm.red[2][lo];
    f32x4 s3 = *(const f32x4*)&sm.red[3][lo];
    f32x4 bv = *(const f32x4*)&bias[col0 + ec + v * 16];
    f32x4 rv = *(const f32x4*)&resid[gbase + v * 16];
    f32x4 o;
#pragma unroll
    for (int e = 0; e < 4; ++e) o[e] = s0[e] + s1[e] + s2[e] + s3[e] + bv[e] + rv[e];
    *(f32x4*)&outF[gbase + v * 16] = o;
  }
}

// ---------------------------------------------------------------------------
// Attention: qkv bf16 [B*N, 3072] -> o bf16 [B*N, 1024] (col = h*64+d)
// grid (B*H=64, N/128=4), 512 threads (8 waves, 16 q-rows each).
// Full K + V^T for one head in LDS; per-wave P buffers (no inner barriers).
// ---------------------------------------------------------------------------
__global__ __launch_bounds__(512, 2)
void attn_k(const bf16* __restrict__ qkv, bf16* __restrict__ o)
{
  __shared__ bf16 Ks[512 * 72];     // [j][d], stride 72
  __shared__ bf16 Vt[64 * 520];     // [d][j], stride 520
  __shared__ bf16 Pl[8][16 * 72];   // per-wave P chunk [i][j_local], 64 cols

  const int tid = threadIdx.x, wave = tid >> 6, lane = tid & 63;
  const int b = blockIdx.x >> 4, h = blockIdx.x & 15;
  const int i0g = blockIdx.y * 128 + wave * 16;
  const bf16* base = qkv + (size_t)b * 512 * 3072;

  { // K -> LDS row-major
    const int jr = tid >> 3, c0 = (tid & 7) * 8;
#pragma unroll
    for (int p = 0; p < 8; ++p) {
      const int j = p * 64 + jr;
      *(bf16x8*)&Ks[j * 72 + c0] =
          *(const bf16x8*)&base[(size_t)j * 3072 + 1024 + h * 64 + c0];
    }
  }
  { // V -> LDS transposed
    const int jr = tid >> 4, d0 = (tid & 15) * 4;
#pragma unroll
    for (int p = 0; p < 16; ++p) {
      const int j = p * 32 + jr;
      bf16x4 v = *(const bf16x4*)&base[(size_t)j * 3072 + 2048 + h * 64 + d0];
      Vt[(d0 + 0) * 520 + j] = v[0];
      Vt[(d0 + 1) * 520 + j] = v[1];
      Vt[(d0 + 2) * 520 + j] = v[2];
      Vt[(d0 + 3) * 520 + j] = v[3];
    }
  }
  bf16x8 qf[2];
  {
    const int qr = i0g + (lane & 15);
#pragma unroll
    for (int t = 0; t < 2; ++t)
      qf[t] = *(const bf16x8*)&base[(size_t)qr * 3072 + h * 64 + t * 32 + (lane >> 4) * 8];
  }
  __syncthreads();

  // S = Q K^T : each wave 16 rows x 512 cols (32 n-tiles, 2 k-steps of 32)
  f32x4 S[32];
#pragma unroll
  for (int nt = 0; nt < 32; ++nt) {
    const bf16* kb = &Ks[(nt * 16 + (lane & 15)) * 72 + (lane >> 4) * 8];
    f32x4 c = {};
    c = __builtin_amdgcn_mfma_f32_16x16x32_bf16(qf[0], *(const bf16x8*)kb, c, 0, 0, 0);
    c = __builtin_amdgcn_mfma_f32_16x16x32_bf16(qf[1], *(const bf16x8*)(kb + 32), c, 0, 0, 0);
    S[nt] = c;
  }

  // softmax over rows (C-layout: row=(lane>>4)*4+r, col=nt*16+(lane&15))
  float mx[4] = {-1e30f, -1e30f, -1e30f, -1e30f};
#pragma unroll
  for (int nt = 0; nt < 32; ++nt)
#pragma unroll
    for (int r = 0; r < 4; ++r) {
      S[nt][r] *= 0.125f;
      mx[r] = fmaxf(mx[r], S[nt][r]);
    }
#pragma unroll
  for (int m = 1; m < 16; m <<= 1)
#pragma unroll
    for (int r = 0; r < 4; ++r) mx[r] = fmaxf(mx[r], __shfl_xor(mx[r], m));
  float sm[4] = {0.f, 0.f, 0.f, 0.f};
#pragma unroll
  for (int nt = 0; nt < 32; ++nt)
#pragma unroll
    for (int r = 0; r < 4; ++r) {
      const float e = __expf(S[nt][r] - mx[r]);
      S[nt][r] = e;
      sm[r] += e;
    }
#pragma unroll
  for (int m = 1; m < 16; m <<= 1)
#pragma unroll
    for (int r = 0; r < 4; ++r) sm[r] += __shfl_xor(sm[r], m);
  float inv[4];
#pragma unroll
  for (int r = 0; r < 4; ++r) inv[r] = 1.f / sm[r];

  // O = P V: P roundtrips per-wave LDS (C-layout -> A-layout), 8 chunks of 64
  f32x4 O[4] = {};
  for (int cch = 0; cch < 8; ++cch) {
#pragma unroll
    for (int t = 0; t < 4; ++t) {
      const int nt = cch * 4 + t;
#pragma unroll
      for (int r = 0; r < 4; ++r)
        Pl[wave][((lane >> 4) * 4 + r) * 72 + t * 16 + (lane & 15)] = (bf16)S[nt][r];
    }
#pragma unroll
    for (int ktile = 0; ktile < 2; ++ktile) {
      bf16x8 pf = *(const bf16x8*)&Pl[wave][(lane & 15) * 72 + ktile * 32 + (lane >> 4) * 8];
#pragma unroll
      for (int dt = 0; dt < 4; ++dt) {
        const bf16* vb = &Vt[(dt * 16 + (lane & 15)) * 520 + cch * 64 + ktile * 32 + (lane >> 4) * 8];
        O[dt] = __builtin_amdgcn_mfma_f32_16x16x32_bf16(pf, *(const bf16x8*)vb, O[dt], 0, 0, 0);
      }
    }
  }

#pragma unroll
  for (int dt = 0; dt < 4; ++dt)
#pragma unroll
    for (int r = 0; r < 4; ++r) {
      const int i = (lane >> 4) * 4 + r;
      const int d = dt * 16 + (lane & 15);
      o[(size_t)(b * 512 + i0g + i) * 1024 + h * 64 + d] = (bf16)(O[dt][r] * inv[r]);
    }
}

// ---------------------------------------------------------------------------
// LayerNorm: x fp32 [rows,1024], fp32 scale/bias -> bf16 out
// ---------------------------------------------------------------------------
__global__ __launch_bounds__(256)
void ln_k(const float* __restrict__ x, const float* __restrict__ sc,
          const float* __restrict__ bi, bf16* __restrict__ out)
{
  const int row = blockIdx.x, tid = threadIdx.x;
  f32x4 a = *(const f32x4*)&x[(size_t)row * 1024 + tid * 4];
  float s  = a[0] + a[1] + a[2] + a[3];
  float s2 = a[0]*a[0] + a[1]*a[1] + a[2]*a[2] + a[3]*a[3];
#pragma unroll
  for (int m = 32; m >= 1; m >>= 1) {
    s  += __shfl_xor(s, m);
    s2 += __shfl_xor(s2, m);
  }
  __shared__ float red[8];
  if ((tid & 63) == 0) { red[tid >> 6] = s; red[4 + (tid >> 6)] = s2; }
  __syncthreads();
  s  = red[0] + red[1] + red[2] + red[3];
  s2 = red[4] + red[5] + red[6] + red[7];
  const float mean = s * (1.f / 1024.f);
  const float var  = s2 * (1.f / 1024.f) - mean * mean;
  const float rs   = rsqrtf(var + 1e-5f);
  bf16x4 ov;
#pragma unroll
  for (int i = 0; i < 4; ++i) {
    const int c = tid * 4 + i;
    ov[i] = (bf16)((a[i] - mean) * rs * sc[c] + bi[c]);
  }
  *(bf16x4*)&out[(size_t)row * 1024 + tid * 4] = ov;
}

// ---------------------------------------------------------------------------
extern "C" void kernel_launch(void* const* d_in, const int* in_sizes, int n_in,
                              void* d_out, int out_size, void* d_ws, size_t ws_size,
                              hipStream_t stream)
{
  const float* x_in = (const float*)d_in[0];
  const float* ln1s = (const float*)d_in[1];
  const float* ln1b = (const float*)d_in[2];
  const float* wqkv = (const float*)d_in[3];
  const float* wout = (const float*)d_in[4];
  const float* bout = (const float*)d_in[5];
  const float* ln2s = (const float*)d_in[6];
  const float* ln2b = (const float*)d_in[7];
  const float* w1   = (const float*)d_in[8];
  const float* b1   = (const float*)d_in[9];
  const float* w2   = (const float*)d_in[10];
  const float* b2   = (const float*)d_in[11];

  char* ws = (char*)d_ws;
  const size_t MB = 1 << 20;
  float* xf   = (float*)(ws);              // 8 MiB fp32 residual stream
  bf16* act   = (bf16*)(ws + 8   * MB);    // 4 MiB: ln out / attn out
  bf16* qg    = (bf16*)(ws + 12  * MB);    // 16 MiB: qkv (12) then gelu (16)
  bf16* qkvT  = (bf16*)(ws + 28  * MB);    // 36 MiB [6][3072,1024]
  bf16* woutT = (bf16*)(ws + 64  * MB);    // 12 MiB [6][1024,1024]
  bf16* w1T   = (bf16*)(ws + 76  * MB);    // 48 MiB [6][4096,1024]
  bf16* w2T   = (bf16*)(ws + 124 * MB);    // 48 MiB [6][1024,4096] (end 172 MiB)

  // transpose-convert all layers' weights to bf16 [N,K]
  convT_k<<<dim3(16, 48, 6), 256, 0, stream>>>(wqkv, qkvT, 1024, 3072);
  convT_k<<<dim3(16, 16, 6), 256, 0, stream>>>(wout, woutT, 1024, 1024);
  convT_k<<<dim3(16, 64, 6), 256, 0, stream>>>(w1, w1T, 1024, 4096);
  convT_k<<<dim3(64, 16, 6), 256, 0, stream>>>(w2, w2T, 4096, 1024);

  for (int l = 0; l < 6; ++l) {
    const float* xres = (l == 0) ? x_in : xf;  // residual-stream input
    ln_k<<<2048, 256, 0, stream>>>(xres, ln1s + l * 1024, ln1b + l * 1024, act);
    gemm128_k<0><<<dim3(16, 24), 256, 0, stream>>>(
        act, qkvT + (size_t)l * 3072 * 1024, nullptr, qg, 2048, 3072, 1024);
    attn_k<<<dim3(64, 4), 512, 0, stream>>>(qg, act);
    gemm64s_k<<<dim3(32, 16), 256, 0, stream>>>(
        act, woutT + (size_t)l * 1024 * 1024, bout + l * 1024, xres, xf,
        2048, 1024, 1024);
    ln_k<<<2048, 256, 0, stream>>>(xf, ln2s + l * 1024, ln2b + l * 1024, act);
    gemm128_k<2><<<dim3(16, 32), 256, 0, stream>>>(
        act, w1T + (size_t)l * 4096 * 1024, b1 + l * 4096, qg, 2048, 4096, 1024);
    float* outp = (l == 5) ? (float*)d_out : xf;
    gemm64s_k<<<dim3(32, 16), 256, 0, stream>>>(
        qg, w2T + (size_t)l * 1024 * 4096, b2 + l * 1024, xf, outp,
        2048, 1024, 4096);
  }
}

// Round 3
// 1223.600 us; speedup vs baseline: 1.0341x; 1.0055x over previous
//
#include <hip/hip_runtime.h>
#include <cstdint>
#include <cstddef>

typedef __bf16 bf16;
typedef __bf16 bf16x4 __attribute__((ext_vector_type(4)));
typedef __bf16 bf16x8 __attribute__((ext_vector_type(8)));
typedef float  f32x4  __attribute__((ext_vector_type(4)));

#define LDS_CAST(p) ((__attribute__((address_space(3))) void*)(p))
#define GLB_CAST(p) ((const __attribute__((address_space(1))) void*)(p))

__device__ __forceinline__ void glds16(const void* g, void* l) {
  // 16B per lane, LDS dst = wave-uniform base + lane*16
  __builtin_amdgcn_global_load_lds(GLB_CAST(g), LDS_CAST(l), 16, 0, 0);
}

// ---------------------------------------------------------------------------
// Transpose-convert (all 6 layers, grid.z = layer): w fp32 [K,N] -> wt bf16 [N,K]
// ---------------------------------------------------------------------------
__global__ __launch_bounds__(256)
void convT_k(const float* __restrict__ w, bf16* __restrict__ wt, int K, int N)
{
  __shared__ bf16 t[64][72];
  const int tid = threadIdx.x;
  const int k0 = blockIdx.x * 64, n0 = blockIdx.y * 64;
  w  += (size_t)blockIdx.z * K * N;
  wt += (size_t)blockIdx.z * K * N;
  const int r = tid >> 4, c = (tid & 15) * 4;
#pragma unroll
  for (int p = 0; p < 4; ++p) {
    const int k = p * 16 + r;
    f32x4 v = *(const f32x4*)&w[(size_t)(k0 + k) * N + n0 + c];
    bf16x4 b = { (bf16)v[0], (bf16)v[1], (bf16)v[2], (bf16)v[3] };
    *(bf16x4*)&t[k][c] = b;
  }
  __syncthreads();
#pragma unroll
  for (int p = 0; p < 4; ++p) {
    const int n = p * 16 + r;
    bf16x4 b = { t[c + 0][n], t[c + 1][n], t[c + 2][n], t[c + 3][n] };
    *(bf16x4*)&wt[(size_t)(n0 + n) * K + k0 + c] = b;
  }
}

// ---------------------------------------------------------------------------
// K=1024 GEMMs (qkv, ff1): barrier-free per-wave tiles.
// Block = 4 waves covering a 128x128 tile as 2x2 of INDEPENDENT 64x64
// per-wave tiles, full K per wave (no split-K, no cross-wave reduce).
// Per wave: private double-buffered LDS (A,B 64x32 each; 16 KB), glds16
// staging, counted s_waitcnt vmcnt(8) 2-deep pipeline, ZERO barriers.
// 4x4 accum -> 16 MFMA per 8 ds_read_b128. LDS XOR-swizzle (both-sides
// involution): 16B slot s of row r holds k-block s ^ ((r>>1)&3), applied by
// pre-swizzling the per-lane GLOBAL source (LDS dest stays linear for
// glds16) and by the fragment-read offset -> conflict-free b128 reads.
// EPI 0: store bf16               EPI 2: +bias, exact GELU, store bf16
// Grid (M/128, N/128), 256 thr, 64KB LDS -> 2 blocks/CU, 8 waves/CU.
// Addressing math identical to the harness-verified gemm64s_k.
// ---------------------------------------------------------------------------
template<int EPI>
__global__ __launch_bounds__(256, 2)
void gemm64w_k(const bf16* __restrict__ A, const bf16* __restrict__ Bt,
               const float* __restrict__ bias, bf16* __restrict__ outB,
               int M, int N, int K)
{
  __shared__ bf16 stage[4][2][2][2048];   // [wave][buf][A=0/B=1][64*32] = 64 KiB

  const int tid  = threadIdx.x;
  const int wave = tid >> 6, lane = tid & 63;
  const int row0 = blockIdx.x * 128 + (wave & 1) * 64;
  const int col0 = blockIdx.y * 128 + (wave >> 1) * 64;

  // staging: 4 glds16 per matrix per 64x32 tile (16 rows x 64B each);
  // per-lane global k-offset pre-swizzled so linear LDS dest ends up swizzled
  const int srow = lane >> 2;                              // row within 16-chunk
  const int ssw  = ((lane & 3) ^ ((lane >> 3) & 3)) << 3;  // swizzled k elems
  const bf16* Ab = A  + (size_t)(row0 + srow) * K + ssw;
  const bf16* Bb = Bt + (size_t)(col0 + srow) * K + ssw;

  // fragment reads: slot = fq ^ ((row>>1)&3), constant per lane
  const int fr  = lane & 15;
  const int fq8 = (((lane >> 4) ^ ((fr >> 1) & 3))) << 3;

  f32x4 acc[4][4] = {};

#define STAGE(buf, kt)                                                         \
  {                                                                            \
    const int k0_ = (kt) << 5;                                                 \
    bf16* pa_ = stage[wave][buf][0];                                           \
    bf16* pb_ = stage[wave][buf][1];                                           \
    _Pragma("unroll")                                                          \
    for (int c_ = 0; c_ < 4; ++c_) {                                           \
      glds16(Ab + (size_t)c_ * 16 * K + k0_, pa_ + c_ * 512);                  \
      glds16(Bb + (size_t)c_ * 16 * K + k0_, pb_ + c_ * 512);                  \
    }                                                                          \
  }

#define COMPUTE(buf)                                                           \
  {                                                                            \
    const bf16* pa_ = stage[wave][buf][0];                                     \
    const bf16* pb_ = stage[wave][buf][1];                                     \
    bf16x8 af[4], bfr[4];                                                      \
    _Pragma("unroll")                                                          \
    for (int t_ = 0; t_ < 4; ++t_) {                                           \
      af[t_]  = *(const bf16x8*)(pa_ + (t_ * 16 + fr) * 32 + fq8);             \
      bfr[t_] = *(const bf16x8*)(pb_ + (t_ * 16 + fr) * 32 + fq8);             \
    }                                                                          \
    __builtin_amdgcn_s_setprio(1);                                             \
    _Pragma("unroll")                                                          \
    for (int i_ = 0; i_ < 4; ++i_)                                             \
      _Pragma("unroll")                                                        \
      for (int j_ = 0; j_ < 4; ++j_)                                           \
        acc[i_][j_] = __builtin_amdgcn_mfma_f32_16x16x32_bf16(                 \
            af[i_], bfr[j_], acc[i_][j_], 0, 0, 0);                            \
    __builtin_amdgcn_s_setprio(0);                                             \
  }

  const int nk = K >> 5;
  STAGE(0, 0);
  for (int kt = 0; kt < nk - 1; ++kt) {
    STAGE((kt + 1) & 1, kt + 1);                       // 16 outstanding
    asm volatile("s_waitcnt vmcnt(8)" ::: "memory");   // oldest 8 = cur tile
    COMPUTE(kt & 1);
  }
  asm volatile("s_waitcnt vmcnt(0)" ::: "memory");
  COMPUTE((nk - 1) & 1);

#undef STAGE
#undef COMPUTE

  // per-wave epilogue, no barriers needed (acc is register-resident)
#pragma unroll
  for (int i = 0; i < 4; ++i) {
    const int rb = row0 + i * 16 + (lane >> 4) * 4;
#pragma unroll
    for (int j = 0; j < 4; ++j) {
      const int c = col0 + j * 16 + fr;
      const float bv = (EPI == 2) ? bias[c] : 0.f;
#pragma unroll
      for (int r = 0; r < 4; ++r) {
        float v = acc[i][j][r] + bv;
        if (EPI == 2) v = 0.5f * v * (1.f + erff(v * 0.70710678118654752f));
        outB[(size_t)(rb + r) * N + c] = (bf16)v;
      }
    }
  }
}

// ---------------------------------------------------------------------------
// N=1024 GEMMs (wout, ff2): barrier-free per-wave split-K.
// 64x64 output tile, 4 waves; wave g owns K-chunk [g*K/4, (g+1)*K/4).
// Each wave: private double-buffered LDS (A,B 64x32 each), glds16 staging,
// counted s_waitcnt vmcnt(8) 2-deep pipeline, NO __syncthreads in K-loop.
// 4x4 accum. LDS XOR-swizzle (both-sides involution, rule #21).
// Final cross-wave reduce via LDS (stride-68 fp32 pad, 2-way max):
// out = sum(acc_w) + bias + resid (fp32; resid may alias out).
// Grid 32x16 = 512 blocks, 256 thr, 68KB LDS -> 2 blocks/CU, 8 waves/CU.
// [harness-verified in round 1 -- DO NOT MODIFY]
// ---------------------------------------------------------------------------
__global__ __launch_bounds__(256, 2)
void gemm64s_k(const bf16* __restrict__ A, const bf16* __restrict__ Bt,
               const float* __restrict__ bias, const float* resid,
               float* outF, int M, int N, int K)
{
  union SMem {
    bf16  stage[4][2][2][2048];   // [wave][buf][A=0/B=1][64*32] = 64 KiB
    float red[4][64 * 68];        // 69632 B (padded stride 68)
  };
  __shared__ SMem sm;

  const int tid  = threadIdx.x;
  const int wave = tid >> 6, lane = tid & 63;
  const int row0 = blockIdx.x * 64, col0 = blockIdx.y * 64;
  const int kChunk = K >> 2;
  const int nk = kChunk >> 5;               // 32-wide K-steps per wave

  // staging: 4 glds16 per matrix per 64x32 tile (16 rows x 64B each);
  // per-lane global k-offset pre-swizzled so linear LDS dest ends up swizzled
  const int srow = lane >> 2;                              // row within 16-chunk
  const int ssw  = ((lane & 3) ^ ((lane >> 3) & 3)) << 3;  // swizzled k elems
  const bf16* Ab = A  + (size_t)(row0 + srow) * K + wave * kChunk + ssw;
  const bf16* Bb = Bt + (size_t)(col0 + srow) * K + wave * kChunk + ssw;

  // fragment reads: slot = fq ^ ((row>>1)&3), constant per lane
  const int fr  = lane & 15;
  const int fq8 = (((lane >> 4) ^ ((fr >> 1) & 3))) << 3;

  f32x4 acc[4][4] = {};

#define STAGE(buf, kt)                                                         \
  {                                                                            \
    const int k0_ = (kt) << 5;                                                 \
    bf16* pa_ = sm.stage[wave][buf][0];                                        \
    bf16* pb_ = sm.stage[wave][buf][1];                                        \
    _Pragma("unroll")                                                          \
    for (int c_ = 0; c_ < 4; ++c_) {                                           \
      glds16(Ab + (size_t)c_ * 16 * K + k0_, pa_ + c_ * 512);                  \
      glds16(Bb + (size_t)c_ * 16 * K + k0_, pb_ + c_ * 512);                  \
    }                                                                          \
  }

#define COMPUTE(buf)                                                           \
  {                                                                            \
    const bf16* pa_ = sm.stage[wave][buf][0];                                  \
    const bf16* pb_ = sm.stage[wave][buf][1];                                  \
    bf16x8 af[4], bfr[4];                                                      \
    _Pragma("unroll")                                                          \
    for (int t_ = 0; t_ < 4; ++t_) {                                           \
      af[t_]  = *(const bf16x8*)(pa_ + (t_ * 16 + fr) * 32 + fq8);             \
      bfr[t_] = *(const bf16x8*)(pb_ + (t_ * 16 + fr) * 32 + fq8);             \
    }                                                                          \
    __builtin_amdgcn_s_setprio(1);                                             \
    _Pragma("unroll")                                                          \
    for (int i_ = 0; i_ < 4; ++i_)                                             \
      _Pragma("unroll")                                                        \
      for (int j_ = 0; j_ < 4; ++j_)                                           \
        acc[i_][j_] = __builtin_amdgcn_mfma_f32_16x16x32_bf16(                 \
            af[i_], bfr[j_], acc[i_][j_], 0, 0, 0);                            \
    __builtin_amdgcn_s_setprio(0);                                             \
  }

  STAGE(0, 0);
  for (int kt = 0; kt < nk - 1; ++kt) {
    STAGE((kt + 1) & 1, kt + 1);                       // 16 outstanding
    asm volatile("s_waitcnt vmcnt(8)" ::: "memory");   // oldest 8 = cur tile
    COMPUTE(kt & 1);
  }
  asm volatile("s_waitcnt vmcnt(0)" ::: "memory");
  COMPUTE((nk - 1) & 1);

#undef STAGE
#undef COMPUTE

  // ---- cross-wave reduction (LDS reused; must fence all waves first) ----
  __syncthreads();
#pragma unroll
  for (int i = 0; i < 4; ++i)
#pragma unroll
    for (int j = 0; j < 4; ++j)
#pragma unroll
      for (int r = 0; r < 4; ++r)
        sm.red[wave][(i * 16 + ((lane >> 4) << 2) + r) * 68 + j * 16 + (lane & 15)] =
            acc[i][j][r];
  __syncthreads();

  const int er = tid >> 2;              // row 0..63
  const int ec = (tid & 3) << 2;        // col quarter-base (stride 16 via v)
  const size_t gbase = (size_t)(row0 + er) * N + col0 + ec;
#pragma unroll
  for (int v = 0; v < 4; ++v) {
    const int lo = er * 68 + ec + v * 16;
    f32x4 s0 = *(const f32x4*)&sm.red[0][lo];
    f32x4 s1 = *(const f32x4*)&sm.red[1][lo];
    f32x4 s2 = *(const f32x4*)&sm.red[2][lo];
    f32x4 s3 = *(const f32x4*)&sm.red[3][lo];
    f32x4 bv = *(const f32x4*)&bias[col0 + ec + v * 16];
    f32x4 rv = *(const f32x4*)&resid[gbase + v * 16];
    f32x4 o;
#pragma unroll
    for (int e = 0; e < 4; ++e) o[e] = s0[e] + s1[e] + s2[e] + s3[e] + bv[e] + rv[e];
    *(f32x4*)&outF[gbase + v * 16] = o;
  }
}

// ---------------------------------------------------------------------------
// Attention: qkv bf16 [B*N, 3072] -> o bf16 [B*N, 1024] (col = h*64+d)
// grid (B*H=64, N/128=4), 512 threads (8 waves, 16 q-rows each).
// Full K + V^T for one head in LDS; per-wave P buffers (no inner barriers).
// ---------------------------------------------------------------------------
__global__ __launch_bounds__(512, 2)
void attn_k(const bf16* __restrict__ qkv, bf16* __restrict__ o)
{
  __shared__ bf16 Ks[512 * 72];     // [j][d], stride 72
  __shared__ bf16 Vt[64 * 520];     // [d][j], stride 520
  __shared__ bf16 Pl[8][16 * 72];   // per-wave P chunk [i][j_local], 64 cols

  const int tid = threadIdx.x, wave = tid >> 6, lane = tid & 63;
  const int b = blockIdx.x >> 4, h = blockIdx.x & 15;
  const int i0g = blockIdx.y * 128 + wave * 16;
  const bf16* base = qkv + (size_t)b * 512 * 3072;

  { // K -> LDS row-major
    const int jr = tid >> 3, c0 = (tid & 7) * 8;
#pragma unroll
    for (int p = 0; p < 8; ++p) {
      const int j = p * 64 + jr;
      *(bf16x8*)&Ks[j * 72 + c0] =
          *(const bf16x8*)&base[(size_t)j * 3072 + 1024 + h * 64 + c0];
    }
  }
  { // V -> LDS transposed
    const int jr = tid >> 4, d0 = (tid & 15) * 4;
#pragma unroll
    for (int p = 0; p < 16; ++p) {
      const int j = p * 32 + jr;
      bf16x4 v = *(const bf16x4*)&base[(size_t)j * 3072 + 2048 + h * 64 + d0];
      Vt[(d0 + 0) * 520 + j] = v[0];
      Vt[(d0 + 1) * 520 + j] = v[1];
      Vt[(d0 + 2) * 520 + j] = v[2];
      Vt[(d0 + 3) * 520 + j] = v[3];
    }
  }
  bf16x8 qf[2];
  {
    const int qr = i0g + (lane & 15);
#pragma unroll
    for (int t = 0; t < 2; ++t)
      qf[t] = *(const bf16x8*)&base[(size_t)qr * 3072 + h * 64 + t * 32 + (lane >> 4) * 8];
  }
  __syncthreads();

  // S = Q K^T : each wave 16 rows x 512 cols (32 n-tiles, 2 k-steps of 32)
  f32x4 S[32];
#pragma unroll
  for (int nt = 0; nt < 32; ++nt) {
    const bf16* kb = &Ks[(nt * 16 + (lane & 15)) * 72 + (lane >> 4) * 8];
    f32x4 c = {};
    c = __builtin_amdgcn_mfma_f32_16x16x32_bf16(qf[0], *(const bf16x8*)kb, c, 0, 0, 0);
    c = __builtin_amdgcn_mfma_f32_16x16x32_bf16(qf[1], *(const bf16x8*)(kb + 32), c, 0, 0, 0);
    S[nt] = c;
  }

  // softmax over rows (C-layout: row=(lane>>4)*4+r, col=nt*16+(lane&15))
  float mx[4] = {-1e30f, -1e30f, -1e30f, -1e30f};
#pragma unroll
  for (int nt = 0; nt < 32; ++nt)
#pragma unroll
    for (int r = 0; r < 4; ++r) {
      S[nt][r] *= 0.125f;
      mx[r] = fmaxf(mx[r], S[nt][r]);
    }
#pragma unroll
  for (int m = 1; m < 16; m <<= 1)
#pragma unroll
    for (int r = 0; r < 4; ++r) mx[r] = fmaxf(mx[r], __shfl_xor(mx[r], m));
  float sm[4] = {0.f, 0.f, 0.f, 0.f};
#pragma unroll
  for (int nt = 0; nt < 32; ++nt)
#pragma unroll
    for (int r = 0; r < 4; ++r) {
      const float e = __expf(S[nt][r] - mx[r]);
      S[nt][r] = e;
      sm[r] += e;
    }
#pragma unroll
  for (int m = 1; m < 16; m <<= 1)
#pragma unroll
    for (int r = 0; r < 4; ++r) sm[r] += __shfl_xor(sm[r], m);
  float inv[4];
#pragma unroll
  for (int r = 0; r < 4; ++r) inv[r] = 1.f / sm[r];

  // O = P V: P roundtrips per-wave LDS (C-layout -> A-layout), 8 chunks of 64
  f32x4 O[4] = {};
  for (int cch = 0; cch < 8; ++cch) {
#pragma unroll
    for (int t = 0; t < 4; ++t) {
      const int nt = cch * 4 + t;
#pragma unroll
      for (int r = 0; r < 4; ++r)
        Pl[wave][((lane >> 4) * 4 + r) * 72 + t * 16 + (lane & 15)] = (bf16)S[nt][r];
    }
#pragma unroll
    for (int ktile = 0; ktile < 2; ++ktile) {
      bf16x8 pf = *(const bf16x8*)&Pl[wave][(lane & 15) * 72 + ktile * 32 + (lane >> 4) * 8];
#pragma unroll
      for (int dt = 0; dt < 4; ++dt) {
        const bf16* vb = &Vt[(dt * 16 + (lane & 15)) * 520 + cch * 64 + ktile * 32 + (lane >> 4) * 8];
        O[dt] = __builtin_amdgcn_mfma_f32_16x16x32_bf16(pf, *(const bf16x8*)vb, O[dt], 0, 0, 0);
      }
    }
  }

#pragma unroll
  for (int dt = 0; dt < 4; ++dt)
#pragma unroll
    for (int r = 0; r < 4; ++r) {
      const int i = (lane >> 4) * 4 + r;
      const int d = dt * 16 + (lane & 15);
      o[(size_t)(b * 512 + i0g + i) * 1024 + h * 64 + d] = (bf16)(O[dt][r] * inv[r]);
    }
}

// ---------------------------------------------------------------------------
// LayerNorm: x fp32 [rows,1024], fp32 scale/bias -> bf16 out
// ---------------------------------------------------------------------------
__global__ __launch_bounds__(256)
void ln_k(const float* __restrict__ x, const float* __restrict__ sc,
          const float* __restrict__ bi, bf16* __restrict__ out)
{
  const int row = blockIdx.x, tid = threadIdx.x;
  f32x4 a = *(const f32x4*)&x[(size_t)row * 1024 + tid * 4];
  float s  = a[0] + a[1] + a[2] + a[3];
  float s2 = a[0]*a[0] + a[1]*a[1] + a[2]*a[2] + a[3]*a[3];
#pragma unroll
  for (int m = 32; m >= 1; m >>= 1) {
    s  += __shfl_xor(s, m);
    s2 += __shfl_xor(s2, m);
  }
  __shared__ float red[8];
  if ((tid & 63) == 0) { red[tid >> 6] = s; red[4 + (tid >> 6)] = s2; }
  __syncthreads();
  s  = red[0] + red[1] + red[2] + red[3];
  s2 = red[4] + red[5] + red[6] + red[7];
  const float mean = s * (1.f / 1024.f);
  const float var  = s2 * (1.f / 1024.f) - mean * mean;
  const float rs   = rsqrtf(var + 1e-5f);
  bf16x4 ov;
#pragma unroll
  for (int i = 0; i < 4; ++i) {
    const int c = tid * 4 + i;
    ov[i] = (bf16)((a[i] - mean) * rs * sc[c] + bi[c]);
  }
  *(bf16x4*)&out[(size_t)row * 1024 + tid * 4] = ov;
}

// ---------------------------------------------------------------------------
extern "C" void kernel_launch(void* const* d_in, const int* in_sizes, int n_in,
                              void* d_out, int out_size, void* d_ws, size_t ws_size,
                              hipStream_t stream)
{
  const float* x_in = (const float*)d_in[0];
  const float* ln1s = (const float*)d_in[1];
  const float* ln1b = (const float*)d_in[2];
  const float* wqkv = (const float*)d_in[3];
  const float* wout = (const float*)d_in[4];
  const float* bout = (const float*)d_in[5];
  const float* ln2s = (const float*)d_in[6];
  const float* ln2b = (const float*)d_in[7];
  const float* w1   = (const float*)d_in[8];
  const float* b1   = (const float*)d_in[9];
  const float* w2   = (const float*)d_in[10];
  const float* b2   = (const float*)d_in[11];

  char* ws = (char*)d_ws;
  const size_t MB = 1 << 20;
  float* xf   = (float*)(ws);              // 8 MiB fp32 residual stream
  bf16* act   = (bf16*)(ws + 8   * MB);    // 4 MiB: ln out / attn out
  bf16* qg    = (bf16*)(ws + 12  * MB);    // 16 MiB: qkv (12) then gelu (16)
  bf16* qkvT  = (bf16*)(ws + 28  * MB);    // 36 MiB [6][3072,1024]
  bf16* woutT = (bf16*)(ws + 64  * MB);    // 12 MiB [6][1024,1024]
  bf16* w1T   = (bf16*)(ws + 76  * MB);    // 48 MiB [6][4096,1024]
  bf16* w2T   = (bf16*)(ws + 124 * MB);    // 48 MiB [6][1024,4096] (end 172 MiB)

  // transpose-convert all layers' weights to bf16 [N,K]
  convT_k<<<dim3(16, 48, 6), 256, 0, stream>>>(wqkv, qkvT, 1024, 3072);
  convT_k<<<dim3(16, 16, 6), 256, 0, stream>>>(wout, woutT, 1024, 1024);
  convT_k<<<dim3(16, 64, 6), 256, 0, stream>>>(w1, w1T, 1024, 4096);
  convT_k<<<dim3(64, 16, 6), 256, 0, stream>>>(w2, w2T, 4096, 1024);

  for (int l = 0; l < 6; ++l) {
    const float* xres = (l == 0) ? x_in : xf;  // residual-stream input
    ln_k<<<2048, 256, 0, stream>>>(xres, ln1s + l * 1024, ln1b + l * 1024, act);
    gemm64w_k<0><<<dim3(16, 24), 256, 0, stream>>>(
        act, qkvT + (size_t)l * 3072 * 1024, nullptr, qg, 2048, 3072, 1024);
    attn_k<<<dim3(64, 4), 512, 0, stream>>>(qg, act);
    gemm64s_k<<<dim3(32, 16), 256, 0, stream>>>(
        act, woutT + (size_t)l * 1024 * 1024, bout + l * 1024, xres, xf,
        2048, 1024, 1024);
    ln_k<<<2048, 256, 0, stream>>>(xf, ln2s + l * 1024, ln2b + l * 1024, act);
    gemm64w_k<2><<<dim3(16, 32), 256, 0, stream>>>(
        act, w1T + (size_t)l * 4096 * 1024, b1 + l * 4096, qg, 2048, 4096, 1024);
    float* outp = (l == 5) ? (float*)d_out : xf;
    gemm64s_k<<<dim3(32, 16), 256, 0, stream>>>(
        qg, w2T + (size_t)l * 1024 * 4096, b2 + l * 1024, xf, outp,
        2048, 1024, 4096);
  }
}

// Round 4
// 1169.469 us; speedup vs baseline: 1.0820x; 1.0463x over previous
//
#include <hip/hip_runtime.h>
#include <cstdint>
#include <cstddef>

typedef __bf16 bf16;
typedef __bf16 bf16x4 __attribute__((ext_vector_type(4)));
typedef __bf16 bf16x8 __attribute__((ext_vector_type(8)));
typedef float  f32x4  __attribute__((ext_vector_type(4)));

#define LDS_CAST(p) ((__attribute__((address_space(3))) void*)(p))
#define GLB_CAST(p) ((const __attribute__((address_space(1))) void*)(p))

__device__ __forceinline__ void glds16(const void* g, void* l) {
  // 16B per lane, LDS dst = wave-uniform base + lane*16
  __builtin_amdgcn_global_load_lds(GLB_CAST(g), LDS_CAST(l), 16, 0, 0);
}

// ---------------------------------------------------------------------------
// Transpose-convert (all 6 layers, grid.z = layer): w fp32 [K,N] -> wt bf16 [N,K]
// ---------------------------------------------------------------------------
__global__ __launch_bounds__(256)
void convT_k(const float* __restrict__ w, bf16* __restrict__ wt, int K, int N)
{
  __shared__ bf16 t[64][72];
  const int tid = threadIdx.x;
  const int k0 = blockIdx.x * 64, n0 = blockIdx.y * 64;
  w  += (size_t)blockIdx.z * K * N;
  wt += (size_t)blockIdx.z * K * N;
  const int r = tid >> 4, c = (tid & 15) * 4;
#pragma unroll
  for (int p = 0; p < 4; ++p) {
    const int k = p * 16 + r;
    f32x4 v = *(const f32x4*)&w[(size_t)(k0 + k) * N + n0 + c];
    bf16x4 b = { (bf16)v[0], (bf16)v[1], (bf16)v[2], (bf16)v[3] };
    *(bf16x4*)&t[k][c] = b;
  }
  __syncthreads();
#pragma unroll
  for (int p = 0; p < 4; ++p) {
    const int n = p * 16 + r;
    bf16x4 b = { t[c + 0][n], t[c + 1][n], t[c + 2][n], t[c + 3][n] };
    *(bf16x4*)&wt[(size_t)(n0 + n) * K + k0 + c] = b;
  }
}

// ---------------------------------------------------------------------------
// K=1024 GEMMs (qkv, ff1): SHARED 128x256 tile, 8 waves as 2x4 of 64x64.
// Reuse: (128+256)*32*2B = 24 KB LDS feeds 128 MFMA -> 87 FLOP per L2 byte
// (vs 32 for per-wave-private 64x64 -- the round-1/3 structures were
// L2-BW-capped at ~15% MfmaUtil; this raises the cap to ~38%).
// Schedule: proven minimum 2-phase -- STAGE(next buf) issued first, then
// ds_read+MFMA on cur, then vmcnt(0)+barrier (stage latency hides under
// compute). Double-buffered LDS = 48 KB.
// Staging: 24 units of 16 rows x 64B; wave w stages units {w, w+8, w+16}
// via glds16 (3/wave/K-step). Per-lane global k pre-swizzled (verified
// involution: 16B slot s of row r holds k-block s ^ ((r>>1)&3)); fragment
// reads apply the same XOR -> conflict-free ds_read_b128.
// T1: bijective chunked XCD swizzle (nwg % 8 == 0 at both call sites) so
// each XCD keeps its 2 B-panels (1 MB) resident in its private L2.
// EPI 0: store bf16               EPI 2: +bias, exact GELU, store bf16
// ---------------------------------------------------------------------------
template<int EPI>
__global__ __launch_bounds__(512, 1)
void gemm2ph_k(const bf16* __restrict__ A, const bf16* __restrict__ Bt,
               const float* __restrict__ bias, bf16* __restrict__ outB,
               int M, int N, int K)
{
  __shared__ bf16 stage[2][12288];   // [buf][A 128x32 (4096) | B 256x32 (8192)]

  const int tid  = threadIdx.x;
  const int wave = tid >> 6, lane = tid & 63;

  // T1 chunked XCD swizzle: HW block f runs on XCD f%8; give each XCD a
  // contiguous tile range -> same-by tiles (shared B panel) colocate.
  const int nwg = gridDim.x * gridDim.y;
  int flat = blockIdx.y * gridDim.x + blockIdx.x;
  flat = (flat & 7) * (nwg >> 3) + (flat >> 3);
  const int bx = flat % gridDim.x, by = flat / gridDim.x;

  const int row0 = bx * 128, col0 = by * 256;
  const int wr = wave >> 2, wc = wave & 3;   // wave's 64x64 sub-tile

  // staging sources (3 units/wave: A rows w*16.., B rows w*16.., B rows 128+w*16..)
  const int srow = lane >> 2;                              // row within 16-chunk
  const int ssw  = ((lane & 3) ^ ((lane >> 3) & 3)) << 3;  // swizzled k elems
  const bf16* src0 = A  + (size_t)(row0 + wave * 16 + srow) * K + ssw;
  const bf16* src1 = Bt + (size_t)(col0 + wave * 16 + srow) * K + ssw;
  const bf16* src2 = Bt + (size_t)(col0 + 128 + wave * 16 + srow) * K + ssw;
  const int d0 = wave * 512;            // elem offsets of the 1KB units
  const int d1 = 4096 + wave * 512;
  const int d2 = 8192 + wave * 512;

  // fragment reads: slot = q ^ ((row>>1)&3); row = t*16+fr keeps it = (fr>>1)&3
  const int fr  = lane & 15;
  const int fq8 = (((lane >> 4) ^ ((fr >> 1) & 3))) << 3;

  f32x4 acc[4][4] = {};

#define STAGE2(buf, kt)                                                        \
  {                                                                            \
    const int k0_ = (kt) << 5;                                                 \
    glds16(src0 + k0_, &stage[buf][d0]);                                       \
    glds16(src1 + k0_, &stage[buf][d1]);                                       \
    glds16(src2 + k0_, &stage[buf][d2]);                                       \
  }

#define COMPUTE2(buf)                                                          \
  {                                                                            \
    const bf16* sb_ = stage[buf];                                              \
    bf16x8 af[4], bfr[4];                                                      \
    _Pragma("unroll")                                                          \
    for (int t_ = 0; t_ < 4; ++t_) {                                           \
      af[t_]  = *(const bf16x8*)&sb_[(wr * 64 + t_ * 16 + fr) * 32 + fq8];     \
      bfr[t_] = *(const bf16x8*)&sb_[4096 + (wc * 64 + t_ * 16 + fr) * 32 + fq8]; \
    }                                                                          \
    __builtin_amdgcn_s_setprio(1);                                             \
    _Pragma("unroll")                                                          \
    for (int i_ = 0; i_ < 4; ++i_)                                             \
      _Pragma("unroll")                                                        \
      for (int j_ = 0; j_ < 4; ++j_)                                           \
        acc[i_][j_] = __builtin_amdgcn_mfma_f32_16x16x32_bf16(                 \
            af[i_], bfr[j_], acc[i_][j_], 0, 0, 0);                            \
    __builtin_amdgcn_s_setprio(0);                                             \
  }

  const int nk = K >> 5;
  STAGE2(0, 0);
  asm volatile("s_waitcnt vmcnt(0)" ::: "memory");
  __syncthreads();

  int cur = 0;
  for (int kt = 0; kt < nk; ++kt) {
    if (kt + 1 < nk) STAGE2(cur ^ 1, kt + 1);   // overlap next-tile staging
    COMPUTE2(cur);
    asm volatile("s_waitcnt vmcnt(0)" ::: "memory");  // own stage loads done
    __syncthreads();                                  // all waves' loads/reads done
    cur ^= 1;
  }

#undef STAGE2
#undef COMPUTE2

  // per-wave epilogue (register acc, disjoint outputs)
#pragma unroll
  for (int i = 0; i < 4; ++i) {
    const int rb = row0 + wr * 64 + i * 16 + (lane >> 4) * 4;
#pragma unroll
    for (int j = 0; j < 4; ++j) {
      const int c = col0 + wc * 64 + j * 16 + fr;
      const float bv = (EPI == 2) ? bias[c] : 0.f;
#pragma unroll
      for (int r = 0; r < 4; ++r) {
        float v = acc[i][j][r] + bv;
        if (EPI == 2) v = 0.5f * v * (1.f + erff(v * 0.70710678118654752f));
        outB[(size_t)(rb + r) * N + c] = (bf16)v;
      }
    }
  }
}

// ---------------------------------------------------------------------------
// N=1024 GEMMs (wout, ff2): barrier-free per-wave split-K.
// [harness-verified in round 1 -- unchanged]
// ---------------------------------------------------------------------------
__global__ __launch_bounds__(256, 2)
void gemm64s_k(const bf16* __restrict__ A, const bf16* __restrict__ Bt,
               const float* __restrict__ bias, const float* resid,
               float* outF, int M, int N, int K)
{
  union SMem {
    bf16  stage[4][2][2][2048];   // [wave][buf][A=0/B=1][64*32] = 64 KiB
    float red[4][64 * 68];        // 69632 B (padded stride 68)
  };
  __shared__ SMem sm;

  const int tid  = threadIdx.x;
  const int wave = tid >> 6, lane = tid & 63;
  const int row0 = blockIdx.x * 64, col0 = blockIdx.y * 64;
  const int kChunk = K >> 2;
  const int nk = kChunk >> 5;               // 32-wide K-steps per wave

  const int srow = lane >> 2;                              // row within 16-chunk
  const int ssw  = ((lane & 3) ^ ((lane >> 3) & 3)) << 3;  // swizzled k elems
  const bf16* Ab = A  + (size_t)(row0 + srow) * K + wave * kChunk + ssw;
  const bf16* Bb = Bt + (size_t)(col0 + srow) * K + wave * kChunk + ssw;

  const int fr  = lane & 15;
  const int fq8 = (((lane >> 4) ^ ((fr >> 1) & 3))) << 3;

  f32x4 acc[4][4] = {};

#define STAGE(buf, kt)                                                         \
  {                                                                            \
    const int k0_ = (kt) << 5;                                                 \
    bf16* pa_ = sm.stage[wave][buf][0];                                        \
    bf16* pb_ = sm.stage[wave][buf][1];                                        \
    _Pragma("unroll")                                                          \
    for (int c_ = 0; c_ < 4; ++c_) {                                           \
      glds16(Ab + (size_t)c_ * 16 * K + k0_, pa_ + c_ * 512);                  \
      glds16(Bb + (size_t)c_ * 16 * K + k0_, pb_ + c_ * 512);                  \
    }                                                                          \
  }

#define COMPUTE(buf)                                                           \
  {                                                                            \
    const bf16* pa_ = sm.stage[wave][buf][0];                                  \
    const bf16* pb_ = sm.stage[wave][buf][1];                                  \
    bf16x8 af[4], bfr[4];                                                      \
    _Pragma("unroll")                                                          \
    for (int t_ = 0; t_ < 4; ++t_) {                                           \
      af[t_]  = *(const bf16x8*)(pa_ + (t_ * 16 + fr) * 32 + fq8);             \
      bfr[t_] = *(const bf16x8*)(pb_ + (t_ * 16 + fr) * 32 + fq8);             \
    }                                                                          \
    __builtin_amdgcn_s_setprio(1);                                             \
    _Pragma("unroll")                                                          \
    for (int i_ = 0; i_ < 4; ++i_)                                             \
      _Pragma("unroll")                                                        \
      for (int j_ = 0; j_ < 4; ++j_)                                           \
        acc[i_][j_] = __builtin_amdgcn_mfma_f32_16x16x32_bf16(                 \
            af[i_], bfr[j_], acc[i_][j_], 0, 0, 0);                            \
    __builtin_amdgcn_s_setprio(0);                                             \
  }

  STAGE(0, 0);
  for (int kt = 0; kt < nk - 1; ++kt) {
    STAGE((kt + 1) & 1, kt + 1);                       // 16 outstanding
    asm volatile("s_waitcnt vmcnt(8)" ::: "memory");   // oldest 8 = cur tile
    COMPUTE(kt & 1);
  }
  asm volatile("s_waitcnt vmcnt(0)" ::: "memory");
  COMPUTE((nk - 1) & 1);

#undef STAGE
#undef COMPUTE

  // ---- cross-wave reduction (LDS reused; must fence all waves first) ----
  __syncthreads();
#pragma unroll
  for (int i = 0; i < 4; ++i)
#pragma unroll
    for (int j = 0; j < 4; ++j)
#pragma unroll
      for (int r = 0; r < 4; ++r)
        sm.red[wave][(i * 16 + ((lane >> 4) << 2) + r) * 68 + j * 16 + (lane & 15)] =
            acc[i][j][r];
  __syncthreads();

  const int er = tid >> 2;              // row 0..63
  const int ec = (tid & 3) << 2;        // col quarter-base (stride 16 via v)
  const size_t gbase = (size_t)(row0 + er) * N + col0 + ec;
#pragma unroll
  for (int v = 0; v < 4; ++v) {
    const int lo = er * 68 + ec + v * 16;
    f32x4 s0 = *(const f32x4*)&sm.red[0][lo];
    f32x4 s1 = *(const f32x4*)&sm.red[1][lo];
    f32x4 s2 = *(const f32x4*)&sm.red[2][lo];
    f32x4 s3 = *(const f32x4*)&sm.red[3][lo];
    f32x4 bv = *(const f32x4*)&bias[col0 + ec + v * 16];
    f32x4 rv = *(const f32x4*)&resid[gbase + v * 16];
    f32x4 o;
#pragma unroll
    for (int e = 0; e < 4; ++e) o[e] = s0[e] + s1[e] + s2[e] + s3[e] + bv[e] + rv[e];
    *(f32x4*)&outF[gbase + v * 16] = o;
  }
}

// ---------------------------------------------------------------------------
// Attention: qkv bf16 [B*N, 3072] -> o bf16 [B*N, 1024] (col = h*64+d)
// grid (B*H=64, N/128=4), 512 threads (8 waves, 16 q-rows each).
// ---------------------------------------------------------------------------
__global__ __launch_bounds__(512, 2)
void attn_k(const bf16* __restrict__ qkv, bf16* __restrict__ o)
{
  __shared__ bf16 Ks[512 * 72];     // [j][d], stride 72
  __shared__ bf16 Vt[64 * 520];     // [d][j], stride 520
  __shared__ bf16 Pl[8][16 * 72];   // per-wave P chunk [i][j_local], 64 cols

  const int tid = threadIdx.x, wave = tid >> 6, lane = tid & 63;
  const int b = blockIdx.x >> 4, h = blockIdx.x & 15;
  const int i0g = blockIdx.y * 128 + wave * 16;
  const bf16* base = qkv + (size_t)b * 512 * 3072;

  { // K -> LDS row-major
    const int jr = tid >> 3, c0 = (tid & 7) * 8;
#pragma unroll
    for (int p = 0; p < 8; ++p) {
      const int j = p * 64 + jr;
      *(bf16x8*)&Ks[j * 72 + c0] =
          *(const bf16x8*)&base[(size_t)j * 3072 + 1024 + h * 64 + c0];
    }
  }
  { // V -> LDS transposed
    const int jr = tid >> 4, d0 = (tid & 15) * 4;
#pragma unroll
    for (int p = 0; p < 16; ++p) {
      const int j = p * 32 + jr;
      bf16x4 v = *(const bf16x4*)&base[(size_t)j * 3072 + 2048 + h * 64 + d0];
      Vt[(d0 + 0) * 520 + j] = v[0];
      Vt[(d0 + 1) * 520 + j] = v[1];
      Vt[(d0 + 2) * 520 + j] = v[2];
      Vt[(d0 + 3) * 520 + j] = v[3];
    }
  }
  bf16x8 qf[2];
  {
    const int qr = i0g + (lane & 15);
#pragma unroll
    for (int t = 0; t < 2; ++t)
      qf[t] = *(const bf16x8*)&base[(size_t)qr * 3072 + h * 64 + t * 32 + (lane >> 4) * 8];
  }
  __syncthreads();

  // S = Q K^T : each wave 16 rows x 512 cols (32 n-tiles, 2 k-steps of 32)
  f32x4 S[32];
#pragma unroll
  for (int nt = 0; nt < 32; ++nt) {
    const bf16* kb = &Ks[(nt * 16 + (lane & 15)) * 72 + (lane >> 4) * 8];
    f32x4 c = {};
    c = __builtin_amdgcn_mfma_f32_16x16x32_bf16(qf[0], *(const bf16x8*)kb, c, 0, 0, 0);
    c = __builtin_amdgcn_mfma_f32_16x16x32_bf16(qf[1], *(const bf16x8*)(kb + 32), c, 0, 0, 0);
    S[nt] = c;
  }

  // softmax over rows (C-layout: row=(lane>>4)*4+r, col=nt*16+(lane&15))
  float mx[4] = {-1e30f, -1e30f, -1e30f, -1e30f};
#pragma unroll
  for (int nt = 0; nt < 32; ++nt)
#pragma unroll
    for (int r = 0; r < 4; ++r) {
      S[nt][r] *= 0.125f;
      mx[r] = fmaxf(mx[r], S[nt][r]);
    }
#pragma unroll
  for (int m = 1; m < 16; m <<= 1)
#pragma unroll
    for (int r = 0; r < 4; ++r) mx[r] = fmaxf(mx[r], __shfl_xor(mx[r], m));
  float sm[4] = {0.f, 0.f, 0.f, 0.f};
#pragma unroll
  for (int nt = 0; nt < 32; ++nt)
#pragma unroll
    for (int r = 0; r < 4; ++r) {
      const float e = __expf(S[nt][r] - mx[r]);
      S[nt][r] = e;
      sm[r] += e;
    }
#pragma unroll
  for (int m = 1; m < 16; m <<= 1)
#pragma unroll
    for (int r = 0; r < 4; ++r) sm[r] += __shfl_xor(sm[r], m);
  float inv[4];
#pragma unroll
  for (int r = 0; r < 4; ++r) inv[r] = 1.f / sm[r];

  // O = P V: P roundtrips per-wave LDS (C-layout -> A-layout), 8 chunks of 64
  f32x4 O[4] = {};
  for (int cch = 0; cch < 8; ++cch) {
#pragma unroll
    for (int t = 0; t < 4; ++t) {
      const int nt = cch * 4 + t;
#pragma unroll
      for (int r = 0; r < 4; ++r)
        Pl[wave][((lane >> 4) * 4 + r) * 72 + t * 16 + (lane & 15)] = (bf16)S[nt][r];
    }
#pragma unroll
    for (int ktile = 0; ktile < 2; ++ktile) {
      bf16x8 pf = *(const bf16x8*)&Pl[wave][(lane & 15) * 72 + ktile * 32 + (lane >> 4) * 8];
#pragma unroll
      for (int dt = 0; dt < 4; ++dt) {
        const bf16* vb = &Vt[(dt * 16 + (lane & 15)) * 520 + cch * 64 + ktile * 32 + (lane >> 4) * 8];
        O[dt] = __builtin_amdgcn_mfma_f32_16x16x32_bf16(pf, *(const bf16x8*)vb, O[dt], 0, 0, 0);
      }
    }
  }

#pragma unroll
  for (int dt = 0; dt < 4; ++dt)
#pragma unroll
    for (int r = 0; r < 4; ++r) {
      const int i = (lane >> 4) * 4 + r;
      const int d = dt * 16 + (lane & 15);
      o[(size_t)(b * 512 + i0g + i) * 1024 + h * 64 + d] = (bf16)(O[dt][r] * inv[r]);
    }
}

// ---------------------------------------------------------------------------
// LayerNorm: x fp32 [rows,1024], fp32 scale/bias -> bf16 out
// ---------------------------------------------------------------------------
__global__ __launch_bounds__(256)
void ln_k(const float* __restrict__ x, const float* __restrict__ sc,
          const float* __restrict__ bi, bf16* __restrict__ out)
{
  const int row = blockIdx.x, tid = threadIdx.x;
  f32x4 a = *(const f32x4*)&x[(size_t)row * 1024 + tid * 4];
  float s  = a[0] + a[1] + a[2] + a[3];
  float s2 = a[0]*a[0] + a[1]*a[1] + a[2]*a[2] + a[3]*a[3];
#pragma unroll
  for (int m = 32; m >= 1; m >>= 1) {
    s  += __shfl_xor(s, m);
    s2 += __shfl_xor(s2, m);
  }
  __shared__ float red[8];
  if ((tid & 63) == 0) { red[tid >> 6] = s; red[4 + (tid >> 6)] = s2; }
  __syncthreads();
  s  = red[0] + red[1] + red[2] + red[3];
  s2 = red[4] + red[5] + red[6] + red[7];
  const float mean = s * (1.f / 1024.f);
  const float var  = s2 * (1.f / 1024.f) - mean * mean;
  const float rs   = rsqrtf(var + 1e-5f);
  bf16x4 ov;
#pragma unroll
  for (int i = 0; i < 4; ++i) {
    const int c = tid * 4 + i;
    ov[i] = (bf16)((a[i] - mean) * rs * sc[c] + bi[c]);
  }
  *(bf16x4*)&out[(size_t)row * 1024 + tid * 4] = ov;
}

// ---------------------------------------------------------------------------
extern "C" void kernel_launch(void* const* d_in, const int* in_sizes, int n_in,
                              void* d_out, int out_size, void* d_ws, size_t ws_size,
                              hipStream_t stream)
{
  const float* x_in = (const float*)d_in[0];
  const float* ln1s = (const float*)d_in[1];
  const float* ln1b = (const float*)d_in[2];
  const float* wqkv = (const float*)d_in[3];
  const float* wout = (const float*)d_in[4];
  const float* bout = (const float*)d_in[5];
  const float* ln2s = (const float*)d_in[6];
  const float* ln2b = (const float*)d_in[7];
  const float* w1   = (const float*)d_in[8];
  const float* b1   = (const float*)d_in[9];
  const float* w2   = (const float*)d_in[10];
  const float* b2   = (const float*)d_in[11];

  char* ws = (char*)d_ws;
  const size_t MB = 1 << 20;
  float* xf   = (float*)(ws);              // 8 MiB fp32 residual stream
  bf16* act   = (bf16*)(ws + 8   * MB);    // 4 MiB: ln out / attn out
  bf16* qg    = (bf16*)(ws + 12  * MB);    // 16 MiB: qkv (12) then gelu (16)
  bf16* qkvT  = (bf16*)(ws + 28  * MB);    // 36 MiB [6][3072,1024]
  bf16* woutT = (bf16*)(ws + 64  * MB);    // 12 MiB [6][1024,1024]
  bf16* w1T   = (bf16*)(ws + 76  * MB);    // 48 MiB [6][4096,1024]
  bf16* w2T   = (bf16*)(ws + 124 * MB);    // 48 MiB [6][1024,4096] (end 172 MiB)

  // transpose-convert all layers' weights to bf16 [N,K]
  convT_k<<<dim3(16, 48, 6), 256, 0, stream>>>(wqkv, qkvT, 1024, 3072);
  convT_k<<<dim3(16, 16, 6), 256, 0, stream>>>(wout, woutT, 1024, 1024);
  convT_k<<<dim3(16, 64, 6), 256, 0, stream>>>(w1, w1T, 1024, 4096);
  convT_k<<<dim3(64, 16, 6), 256, 0, stream>>>(w2, w2T, 4096, 1024);

  for (int l = 0; l < 6; ++l) {
    const float* xres = (l == 0) ? x_in : xf;  // residual-stream input
    ln_k<<<2048, 256, 0, stream>>>(xres, ln1s + l * 1024, ln1b + l * 1024, act);
    gemm2ph_k<0><<<dim3(16, 12), 512, 0, stream>>>(
        act, qkvT + (size_t)l * 3072 * 1024, nullptr, qg, 2048, 3072, 1024);
    attn_k<<<dim3(64, 4), 512, 0, stream>>>(qg, act);
    gemm64s_k<<<dim3(32, 16), 256, 0, stream>>>(
        act, woutT + (size_t)l * 1024 * 1024, bout + l * 1024, xres, xf,
        2048, 1024, 1024);
    ln_k<<<2048, 256, 0, stream>>>(xf, ln2s + l * 1024, ln2b + l * 1024, act);
    gemm2ph_k<2><<<dim3(16, 16), 512, 0, stream>>>(
        act, w1T + (size_t)l * 4096 * 1024, b1 + l * 4096, qg, 2048, 4096, 1024);
    float* outp = (l == 5) ? (float*)d_out : xf;
    gemm64s_k<<<dim3(32, 16), 256, 0, stream>>>(
        qg, w2T + (size_t)l * 1024 * 4096, b2 + l * 1024, xf, outp,
        2048, 1024, 4096);
  }
}

// Round 5
// 1105.556 us; speedup vs baseline: 1.1445x; 1.0578x over previous
//
#include <hip/hip_runtime.h>
#include <cstdint>
#include <cstddef>

typedef __bf16 bf16;
typedef __bf16 bf16x4 __attribute__((ext_vector_type(4)));
typedef __bf16 bf16x8 __attribute__((ext_vector_type(8)));
typedef float  f32x4  __attribute__((ext_vector_type(4)));

#define LDS_CAST(p) ((__attribute__((address_space(3))) void*)(p))
#define GLB_CAST(p) ((const __attribute__((address_space(1))) void*)(p))

__device__ __forceinline__ void glds16(const void* g, void* l) {
  // 16B per lane, LDS dst = wave-uniform base + lane*16
  __builtin_amdgcn_global_load_lds(GLB_CAST(g), LDS_CAST(l), 16, 0, 0);
}

// ---------------------------------------------------------------------------
// Transpose-convert (all 6 layers, grid.z = layer): w fp32 [K,N] -> wt bf16 [N,K]
// ---------------------------------------------------------------------------
__global__ __launch_bounds__(256)
void convT_k(const float* __restrict__ w, bf16* __restrict__ wt, int K, int N)
{
  __shared__ bf16 t[64][72];
  const int tid = threadIdx.x;
  const int k0 = blockIdx.x * 64, n0 = blockIdx.y * 64;
  w  += (size_t)blockIdx.z * K * N;
  wt += (size_t)blockIdx.z * K * N;
  const int r = tid >> 4, c = (tid & 15) * 4;
#pragma unroll
  for (int p = 0; p < 4; ++p) {
    const int k = p * 16 + r;
    f32x4 v = *(const f32x4*)&w[(size_t)(k0 + k) * N + n0 + c];
    bf16x4 b = { (bf16)v[0], (bf16)v[1], (bf16)v[2], (bf16)v[3] };
    *(bf16x4*)&t[k][c] = b;
  }
  __syncthreads();
#pragma unroll
  for (int p = 0; p < 4; ++p) {
    const int n = p * 16 + r;
    bf16x4 b = { t[c + 0][n], t[c + 1][n], t[c + 2][n], t[c + 3][n] };
    *(bf16x4*)&wt[(size_t)(n0 + n) * K + k0 + c] = b;
  }
}

// ---------------------------------------------------------------------------
// K=1024 GEMMs (qkv, ff1): SHARED 128x256 tile, 8 waves as 2x4 of 64x64,
// 4-buffer LDS ring (96 KB), 3-K-steps-ahead prefetch, counted vmcnt(6)
// (T4: never drain to 0 in the loop), RAW s_barrier (no implicit vmcnt
// drain -- __syncthreads would void the pipeline). 3 steps of compute
// (~900cy) covers HBM latency of the glds16 prefetch.
// Correctness: per iter, own vmcnt(6) [stage t landed] -> s_barrier ->
// all waves' stage-t in LDS before any read. STAGE(t+3) overwrites buf
// (t-1)&3, whose reads completed before this iter's barrier. ds_reads are
// consumed by MFMAs (compiler lgkmcnt) before the next barrier.
// Staging: 24 units of 16 rows x 64B; wave w stages units {w, w+8, w+16};
// per-lane global k pre-swizzled (verified involution: 16B slot s of row r
// holds k-block s ^ ((r>>1)&3)); fragment reads apply the same XOR ->
// conflict-free ds_read_b128.
// T1: bijective chunked XCD swizzle (nwg % 8 == 0 at both call sites).
// EPI 0: store bf16               EPI 2: +bias, exact GELU, store bf16
// ---------------------------------------------------------------------------
template<int EPI>
__global__ __launch_bounds__(512, 1)
void gemm4r_k(const bf16* __restrict__ A, const bf16* __restrict__ Bt,
              const float* __restrict__ bias, bf16* __restrict__ outB,
              int M, int N, int K)
{
  __shared__ bf16 stage[4][12288];   // ring: [buf][A 128x32 (4096) | B 256x32 (8192)]

  const int tid  = threadIdx.x;
  const int wave = tid >> 6, lane = tid & 63;

  // T1 chunked XCD swizzle
  const int nwg = gridDim.x * gridDim.y;
  int flat = blockIdx.y * gridDim.x + blockIdx.x;
  flat = (flat & 7) * (nwg >> 3) + (flat >> 3);
  const int bx = flat % gridDim.x, by = flat / gridDim.x;

  const int row0 = bx * 128, col0 = by * 256;
  const int wr = wave >> 2, wc = wave & 3;   // wave's 64x64 sub-tile

  // staging sources (3 units/wave: A rows w*16.., B rows w*16.., B rows 128+w*16..)
  const int srow = lane >> 2;                              // row within 16-chunk
  const int ssw  = ((lane & 3) ^ ((lane >> 3) & 3)) << 3;  // swizzled k elems
  const bf16* src0 = A  + (size_t)(row0 + wave * 16 + srow) * K + ssw;
  const bf16* src1 = Bt + (size_t)(col0 + wave * 16 + srow) * K + ssw;
  const bf16* src2 = Bt + (size_t)(col0 + 128 + wave * 16 + srow) * K + ssw;
  const int d0 = wave * 512;            // elem offsets of the 1KB units
  const int d1 = 4096 + wave * 512;
  const int d2 = 8192 + wave * 512;

  // fragment reads: slot = q ^ ((row>>1)&3); row = t*16+fr keeps it = (fr>>1)&3
  const int fr  = lane & 15;
  const int fq8 = (((lane >> 4) ^ ((fr >> 1) & 3))) << 3;

  f32x4 acc[4][4] = {};

#define STAGE4(buf, kt)                                                        \
  {                                                                            \
    const int k0_ = (kt) << 5;                                                 \
    glds16(src0 + k0_, &stage[buf][d0]);                                       \
    glds16(src1 + k0_, &stage[buf][d1]);                                       \
    glds16(src2 + k0_, &stage[buf][d2]);                                       \
  }

#define COMPUTE4(buf)                                                          \
  {                                                                            \
    const bf16* sb_ = stage[buf];                                              \
    bf16x8 af[4], bfr[4];                                                      \
    _Pragma("unroll")                                                          \
    for (int t_ = 0; t_ < 4; ++t_) {                                           \
      af[t_]  = *(const bf16x8*)&sb_[(wr * 64 + t_ * 16 + fr) * 32 + fq8];     \
      bfr[t_] = *(const bf16x8*)&sb_[4096 + (wc * 64 + t_ * 16 + fr) * 32 + fq8]; \
    }                                                                          \
    __builtin_amdgcn_s_setprio(1);                                             \
    _Pragma("unroll")                                                          \
    for (int i_ = 0; i_ < 4; ++i_)                                             \
      _Pragma("unroll")                                                        \
      for (int j_ = 0; j_ < 4; ++j_)                                           \
        acc[i_][j_] = __builtin_amdgcn_mfma_f32_16x16x32_bf16(                 \
            af[i_], bfr[j_], acc[i_][j_], 0, 0, 0);                            \
    __builtin_amdgcn_s_setprio(0);                                             \
  }

  const int nk = K >> 5;                 // 32 for K=1024 (>= 3 required)
  STAGE4(0, 0);
  STAGE4(1, 1);
  STAGE4(2, 2);                          // 9 loads in flight

  for (int kt = 0; kt < nk - 2; ++kt) {
    // own stage-kt loads landed (<=6 remain: stages kt+1, kt+2)
    asm volatile("s_waitcnt vmcnt(6)" ::: "memory");
    __builtin_amdgcn_s_barrier();        // raw: no vmcnt drain
    __builtin_amdgcn_sched_barrier(0);
    if (kt + 3 < nk) STAGE4((kt + 3) & 3, kt + 3);
    COMPUTE4(kt & 3);
  }
  asm volatile("s_waitcnt vmcnt(3)" ::: "memory");
  __builtin_amdgcn_s_barrier();
  __builtin_amdgcn_sched_barrier(0);
  COMPUTE4((nk - 2) & 3);
  asm volatile("s_waitcnt vmcnt(0)" ::: "memory");
  __builtin_amdgcn_s_barrier();
  __builtin_amdgcn_sched_barrier(0);
  COMPUTE4((nk - 1) & 3);

#undef STAGE4
#undef COMPUTE4

  // per-wave epilogue (register acc, disjoint outputs)
#pragma unroll
  for (int i = 0; i < 4; ++i) {
    const int rb = row0 + wr * 64 + i * 16 + (lane >> 4) * 4;
#pragma unroll
    for (int j = 0; j < 4; ++j) {
      const int c = col0 + wc * 64 + j * 16 + fr;
      const float bv = (EPI == 2) ? bias[c] : 0.f;
#pragma unroll
      for (int r = 0; r < 4; ++r) {
        float v = acc[i][j][r] + bv;
        if (EPI == 2) v = 0.5f * v * (1.f + erff(v * 0.70710678118654752f));
        outB[(size_t)(rb + r) * N + c] = (bf16)v;
      }
    }
  }
}

// ---------------------------------------------------------------------------
// N=1024 GEMMs (wout, ff2): barrier-free per-wave split-K.
// [harness-verified in round 1 -- unchanged]
// ---------------------------------------------------------------------------
__global__ __launch_bounds__(256, 2)
void gemm64s_k(const bf16* __restrict__ A, const bf16* __restrict__ Bt,
               const float* __restrict__ bias, const float* resid,
               float* outF, int M, int N, int K)
{
  union SMem {
    bf16  stage[4][2][2][2048];   // [wave][buf][A=0/B=1][64*32] = 64 KiB
    float red[4][64 * 68];        // 69632 B (padded stride 68)
  };
  __shared__ SMem sm;

  const int tid  = threadIdx.x;
  const int wave = tid >> 6, lane = tid & 63;
  const int row0 = blockIdx.x * 64, col0 = blockIdx.y * 64;
  const int kChunk = K >> 2;
  const int nk = kChunk >> 5;               // 32-wide K-steps per wave

  const int srow = lane >> 2;                              // row within 16-chunk
  const int ssw  = ((lane & 3) ^ ((lane >> 3) & 3)) << 3;  // swizzled k elems
  const bf16* Ab = A  + (size_t)(row0 + srow) * K + wave * kChunk + ssw;
  const bf16* Bb = Bt + (size_t)(col0 + srow) * K + wave * kChunk + ssw;

  const int fr  = lane & 15;
  const int fq8 = (((lane >> 4) ^ ((fr >> 1) & 3))) << 3;

  f32x4 acc[4][4] = {};

#define STAGE(buf, kt)                                                         \
  {                                                                            \
    const int k0_ = (kt) << 5;                                                 \
    bf16* pa_ = sm.stage[wave][buf][0];                                        \
    bf16* pb_ = sm.stage[wave][buf][1];                                        \
    _Pragma("unroll")                                                          \
    for (int c_ = 0; c_ < 4; ++c_) {                                           \
      glds16(Ab + (size_t)c_ * 16 * K + k0_, pa_ + c_ * 512);                  \
      glds16(Bb + (size_t)c_ * 16 * K + k0_, pb_ + c_ * 512);                  \
    }                                                                          \
  }

#define COMPUTE(buf)                                                           \
  {                                                                            \
    const bf16* pa_ = sm.stage[wave][buf][0];                                  \
    const bf16* pb_ = sm.stage[wave][buf][1];                                  \
    bf16x8 af[4], bfr[4];                                                      \
    _Pragma("unroll")                                                          \
    for (int t_ = 0; t_ < 4; ++t_) {                                           \
      af[t_]  = *(const bf16x8*)(pa_ + (t_ * 16 + fr) * 32 + fq8);             \
      bfr[t_] = *(const bf16x8*)(pb_ + (t_ * 16 + fr) * 32 + fq8);             \
    }                                                                          \
    __builtin_amdgcn_s_setprio(1);                                             \
    _Pragma("unroll")                                                          \
    for (int i_ = 0; i_ < 4; ++i_)                                             \
      _Pragma("unroll")                                                        \
      for (int j_ = 0; j_ < 4; ++j_)                                           \
        acc[i_][j_] = __builtin_amdgcn_mfma_f32_16x16x32_bf16(                 \
            af[i_], bfr[j_], acc[i_][j_], 0, 0, 0);                            \
    __builtin_amdgcn_s_setprio(0);                                             \
  }

  STAGE(0, 0);
  for (int kt = 0; kt < nk - 1; ++kt) {
    STAGE((kt + 1) & 1, kt + 1);                       // 16 outstanding
    asm volatile("s_waitcnt vmcnt(8)" ::: "memory");   // oldest 8 = cur tile
    COMPUTE(kt & 1);
  }
  asm volatile("s_waitcnt vmcnt(0)" ::: "memory");
  COMPUTE((nk - 1) & 1);

#undef STAGE
#undef COMPUTE

  // ---- cross-wave reduction (LDS reused; must fence all waves first) ----
  __syncthreads();
#pragma unroll
  for (int i = 0; i < 4; ++i)
#pragma unroll
    for (int j = 0; j < 4; ++j)
#pragma unroll
      for (int r = 0; r < 4; ++r)
        sm.red[wave][(i * 16 + ((lane >> 4) << 2) + r) * 68 + j * 16 + (lane & 15)] =
            acc[i][j][r];
  __syncthreads();

  const int er = tid >> 2;              // row 0..63
  const int ec = (tid & 3) << 2;        // col quarter-base (stride 16 via v)
  const size_t gbase = (size_t)(row0 + er) * N + col0 + ec;
#pragma unroll
  for (int v = 0; v < 4; ++v) {
    const int lo = er * 68 + ec + v * 16;
    f32x4 s0 = *(const f32x4*)&sm.red[0][lo];
    f32x4 s1 = *(const f32x4*)&sm.red[1][lo];
    f32x4 s2 = *(const f32x4*)&sm.red[2][lo];
    f32x4 s3 = *(const f32x4*)&sm.red[3][lo];
    f32x4 bv = *(const f32x4*)&bias[col0 + ec + v * 16];
    f32x4 rv = *(const f32x4*)&resid[gbase + v * 16];
    f32x4 o;
#pragma unroll
    for (int e = 0; e < 4; ++e) o[e] = s0[e] + s1[e] + s2[e] + s3[e] + bv[e] + rv[e];
    *(f32x4*)&outF[gbase + v * 16] = o;
  }
}

// ---------------------------------------------------------------------------
// Attention: qkv bf16 [B*N, 3072] -> o bf16 [B*N, 1024] (col = h*64+d)
// grid (B*H=64, N/128=4), 512 threads (8 waves, 16 q-rows each).
// ---------------------------------------------------------------------------
__global__ __launch_bounds__(512, 2)
void attn_k(const bf16* __restrict__ qkv, bf16* __restrict__ o)
{
  __shared__ bf16 Ks[512 * 72];     // [j][d], stride 72
  __shared__ bf16 Vt[64 * 520];     // [d][j], stride 520
  __shared__ bf16 Pl[8][16 * 72];   // per-wave P chunk [i][j_local], 64 cols

  const int tid = threadIdx.x, wave = tid >> 6, lane = tid & 63;
  const int b = blockIdx.x >> 4, h = blockIdx.x & 15;
  const int i0g = blockIdx.y * 128 + wave * 16;
  const bf16* base = qkv + (size_t)b * 512 * 3072;

  { // K -> LDS row-major
    const int jr = tid >> 3, c0 = (tid & 7) * 8;
#pragma unroll
    for (int p = 0; p < 8; ++p) {
      const int j = p * 64 + jr;
      *(bf16x8*)&Ks[j * 72 + c0] =
          *(const bf16x8*)&base[(size_t)j * 3072 + 1024 + h * 64 + c0];
    }
  }
  { // V -> LDS transposed
    const int jr = tid >> 4, d0 = (tid & 15) * 4;
#pragma unroll
    for (int p = 0; p < 16; ++p) {
      const int j = p * 32 + jr;
      bf16x4 v = *(const bf16x4*)&base[(size_t)j * 3072 + 2048 + h * 64 + d0];
      Vt[(d0 + 0) * 520 + j] = v[0];
      Vt[(d0 + 1) * 520 + j] = v[1];
      Vt[(d0 + 2) * 520 + j] = v[2];
      Vt[(d0 + 3) * 520 + j] = v[3];
    }
  }
  bf16x8 qf[2];
  {
    const int qr = i0g + (lane & 15);
#pragma unroll
    for (int t = 0; t < 2; ++t)
      qf[t] = *(const bf16x8*)&base[(size_t)qr * 3072 + h * 64 + t * 32 + (lane >> 4) * 8];
  }
  __syncthreads();

  // S = Q K^T : each wave 16 rows x 512 cols (32 n-tiles, 2 k-steps of 32)
  f32x4 S[32];
#pragma unroll
  for (int nt = 0; nt < 32; ++nt) {
    const bf16* kb = &Ks[(nt * 16 + (lane & 15)) * 72 + (lane >> 4) * 8];
    f32x4 c = {};
    c = __builtin_amdgcn_mfma_f32_16x16x32_bf16(qf[0], *(const bf16x8*)kb, c, 0, 0, 0);
    c = __builtin_amdgcn_mfma_f32_16x16x32_bf16(qf[1], *(const bf16x8*)(kb + 32), c, 0, 0, 0);
    S[nt] = c;
  }

  // softmax over rows (C-layout: row=(lane>>4)*4+r, col=nt*16+(lane&15))
  float mx[4] = {-1e30f, -1e30f, -1e30f, -1e30f};
#pragma unroll
  for (int nt = 0; nt < 32; ++nt)
#pragma unroll
    for (int r = 0; r < 4; ++r) {
      S[nt][r] *= 0.125f;
      mx[r] = fmaxf(mx[r], S[nt][r]);
    }
#pragma unroll
  for (int m = 1; m < 16; m <<= 1)
#pragma unroll
    for (int r = 0; r < 4; ++r) mx[r] = fmaxf(mx[r], __shfl_xor(mx[r], m));
  float sm[4] = {0.f, 0.f, 0.f, 0.f};
#pragma unroll
  for (int nt = 0; nt < 32; ++nt)
#pragma unroll
    for (int r = 0; r < 4; ++r) {
      const float e = __expf(S[nt][r] - mx[r]);
      S[nt][r] = e;
      sm[r] += e;
    }
#pragma unroll
  for (int m = 1; m < 16; m <<= 1)
#pragma unroll
    for (int r = 0; r < 4; ++r) sm[r] += __shfl_xor(sm[r], m);
  float inv[4];
#pragma unroll
  for (int r = 0; r < 4; ++r) inv[r] = 1.f / sm[r];

  // O = P V: P roundtrips per-wave LDS (C-layout -> A-layout), 8 chunks of 64
  f32x4 O[4] = {};
  for (int cch = 0; cch < 8; ++cch) {
#pragma unroll
    for (int t = 0; t < 4; ++t) {
      const int nt = cch * 4 + t;
#pragma unroll
      for (int r = 0; r < 4; ++r)
        Pl[wave][((lane >> 4) * 4 + r) * 72 + t * 16 + (lane & 15)] = (bf16)S[nt][r];
    }
#pragma unroll
    for (int ktile = 0; ktile < 2; ++ktile) {
      bf16x8 pf = *(const bf16x8*)&Pl[wave][(lane & 15) * 72 + ktile * 32 + (lane >> 4) * 8];
#pragma unroll
      for (int dt = 0; dt < 4; ++dt) {
        const bf16* vb = &Vt[(dt * 16 + (lane & 15)) * 520 + cch * 64 + ktile * 32 + (lane >> 4) * 8];
        O[dt] = __builtin_amdgcn_mfma_f32_16x16x32_bf16(pf, *(const bf16x8*)vb, O[dt], 0, 0, 0);
      }
    }
  }

#pragma unroll
  for (int dt = 0; dt < 4; ++dt)
#pragma unroll
    for (int r = 0; r < 4; ++r) {
      const int i = (lane >> 4) * 4 + r;
      const int d = dt * 16 + (lane & 15);
      o[(size_t)(b * 512 + i0g + i) * 1024 + h * 64 + d] = (bf16)(O[dt][r] * inv[r]);
    }
}

// ---------------------------------------------------------------------------
// LayerNorm: x fp32 [rows,1024], fp32 scale/bias -> bf16 out
// ---------------------------------------------------------------------------
__global__ __launch_bounds__(256)
void ln_k(const float* __restrict__ x, const float* __restrict__ sc,
          const float* __restrict__ bi, bf16* __restrict__ out)
{
  const int row = blockIdx.x, tid = threadIdx.x;
  f32x4 a = *(const f32x4*)&x[(size_t)row * 1024 + tid * 4];
  float s  = a[0] + a[1] + a[2] + a[3];
  float s2 = a[0]*a[0] + a[1]*a[1] + a[2]*a[2] + a[3]*a[3];
#pragma unroll
  for (int m = 32; m >= 1; m >>= 1) {
    s  += __shfl_xor(s, m);
    s2 += __shfl_xor(s2, m);
  }
  __shared__ float red[8];
  if ((tid & 63) == 0) { red[tid >> 6] = s; red[4 + (tid >> 6)] = s2; }
  __syncthreads();
  s  = red[0] + red[1] + red[2] + red[3];
  s2 = red[4] + red[5] + red[6] + red[7];
  const float mean = s * (1.f / 1024.f);
  const float var  = s2 * (1.f / 1024.f) - mean * mean;
  const float rs   = rsqrtf(var + 1e-5f);
  bf16x4 ov;
#pragma unroll
  for (int i = 0; i < 4; ++i) {
    const int c = tid * 4 + i;
    ov[i] = (bf16)((a[i] - mean) * rs * sc[c] + bi[c]);
  }
  *(bf16x4*)&out[(size_t)row * 1024 + tid * 4] = ov;
}

// ---------------------------------------------------------------------------
extern "C" void kernel_launch(void* const* d_in, const int* in_sizes, int n_in,
                              void* d_out, int out_size, void* d_ws, size_t ws_size,
                              hipStream_t stream)
{
  const float* x_in = (const float*)d_in[0];
  const float* ln1s = (const float*)d_in[1];
  const float* ln1b = (const float*)d_in[2];
  const float* wqkv = (const float*)d_in[3];
  const float* wout = (const float*)d_in[4];
  const float* bout = (const float*)d_in[5];
  const float* ln2s = (const float*)d_in[6];
  const float* ln2b = (const float*)d_in[7];
  const float* w1   = (const float*)d_in[8];
  const float* b1   = (const float*)d_in[9];
  const float* w2   = (const float*)d_in[10];
  const float* b2   = (const float*)d_in[11];

  char* ws = (char*)d_ws;
  const size_t MB = 1 << 20;
  float* xf   = (float*)(ws);              // 8 MiB fp32 residual stream
  bf16* act   = (bf16*)(ws + 8   * MB);    // 4 MiB: ln out / attn out
  bf16* qg    = (bf16*)(ws + 12  * MB);    // 16 MiB: qkv (12) then gelu (16)
  bf16* qkvT  = (bf16*)(ws + 28  * MB);    // 36 MiB [6][3072,1024]
  bf16* woutT = (bf16*)(ws + 64  * MB);    // 12 MiB [6][1024,1024]
  bf16* w1T   = (bf16*)(ws + 76  * MB);    // 48 MiB [6][4096,1024]
  bf16* w2T   = (bf16*)(ws + 124 * MB);    // 48 MiB [6][1024,4096] (end 172 MiB)

  // transpose-convert all layers' weights to bf16 [N,K]
  convT_k<<<dim3(16, 48, 6), 256, 0, stream>>>(wqkv, qkvT, 1024, 3072);
  convT_k<<<dim3(16, 16, 6), 256, 0, stream>>>(wout, woutT, 1024, 1024);
  convT_k<<<dim3(16, 64, 6), 256, 0, stream>>>(w1, w1T, 1024, 4096);
  convT_k<<<dim3(64, 16, 6), 256, 0, stream>>>(w2, w2T, 4096, 1024);

  for (int l = 0; l < 6; ++l) {
    const float* xres = (l == 0) ? x_in : xf;  // residual-stream input
    ln_k<<<2048, 256, 0, stream>>>(xres, ln1s + l * 1024, ln1b + l * 1024, act);
    gemm4r_k<0><<<dim3(16, 12), 512, 0, stream>>>(
        act, qkvT + (size_t)l * 3072 * 1024, nullptr, qg, 2048, 3072, 1024);
    attn_k<<<dim3(64, 4), 512, 0, stream>>>(qg, act);
    gemm64s_k<<<dim3(32, 16), 256, 0, stream>>>(
        act, woutT + (size_t)l * 1024 * 1024, bout + l * 1024, xres, xf,
        2048, 1024, 1024);
    ln_k<<<2048, 256, 0, stream>>>(xf, ln2s + l * 1024, ln2b + l * 1024, act);
    gemm4r_k<2><<<dim3(16, 16), 512, 0, stream>>>(
        act, w1T + (size_t)l * 4096 * 1024, b1 + l * 4096, qg, 2048, 4096, 1024);
    float* outp = (l == 5) ? (float*)d_out : xf;
    gemm64s_k<<<dim3(32, 16), 256, 0, stream>>>(
        qg, w2T + (size_t)l * 1024 * 4096, b2 + l * 1024, xf, outp,
        2048, 1024, 4096);
  }
}

// Round 6
// 1086.746 us; speedup vs baseline: 1.1644x; 1.0173x over previous
//
#include <hip/hip_runtime.h>
#include <cstdint>
#include <cstddef>

typedef __bf16 bf16;
typedef __bf16 bf16x4 __attribute__((ext_vector_type(4)));
typedef __bf16 bf16x8 __attribute__((ext_vector_type(8)));
typedef float  f32x4  __attribute__((ext_vector_type(4)));

#define LDS_CAST(p) ((__attribute__((address_space(3))) void*)(p))
#define GLB_CAST(p) ((const __attribute__((address_space(1))) void*)(p))

__device__ __forceinline__ void glds16(const void* g, void* l) {
  // 16B per lane, LDS dst = wave-uniform base + lane*16
  __builtin_amdgcn_global_load_lds(GLB_CAST(g), LDS_CAST(l), 16, 0, 0);
}

// ---------------------------------------------------------------------------
// Transpose-convert (all 6 layers, grid.z = layer): w fp32 [K,N] -> wt bf16 [N,K]
// ---------------------------------------------------------------------------
__global__ __launch_bounds__(256)
void convT_k(const float* __restrict__ w, bf16* __restrict__ wt, int K, int N)
{
  __shared__ bf16 t[64][72];
  const int tid = threadIdx.x;
  const int k0 = blockIdx.x * 64, n0 = blockIdx.y * 64;
  w  += (size_t)blockIdx.z * K * N;
  wt += (size_t)blockIdx.z * K * N;
  const int r = tid >> 4, c = (tid & 15) * 4;
#pragma unroll
  for (int p = 0; p < 4; ++p) {
    const int k = p * 16 + r;
    f32x4 v = *(const f32x4*)&w[(size_t)(k0 + k) * N + n0 + c];
    bf16x4 b = { (bf16)v[0], (bf16)v[1], (bf16)v[2], (bf16)v[3] };
    *(bf16x4*)&t[k][c] = b;
  }
  __syncthreads();
#pragma unroll
  for (int p = 0; p < 4; ++p) {
    const int n = p * 16 + r;
    bf16x4 b = { t[c + 0][n], t[c + 1][n], t[c + 2][n], t[c + 3][n] };
    *(bf16x4*)&wt[(size_t)(n0 + n) * K + k0 + c] = b;
  }
}

// ---------------------------------------------------------------------------
// Deep-ring GEMM: SHARED 128x256 tile, 8 waves as 2x4 of 64x64,
// 6-buffer LDS ring (144 KB), 5-K-steps-ahead prefetch, counted vmcnt(12)
// in the loop (T4: never drain to 0), RAW s_barrier (no implicit vmcnt
// drain). Tail drains 12/9/6/3/0.
// blockIdx.z = K-chunk (split-K across blocks): kBase = z*Kchunk, A/B row
// stride = ldK. EPI 3 writes fp32 partials to outP + z*M*N (reduced by
// red4_k); EPI 0/2 are the fused bf16 epilogues (gridDim.z == 1).
// Staging: 24 units of 16 rows x 64B; wave w stages units {w, w+8, w+16};
// per-lane global k pre-swizzled (verified involution: 16B slot s of row r
// holds k-block s ^ ((r>>1)&3)); fragment reads apply the same XOR ->
// conflict-free ds_read_b128.
// T1: bijective chunked XCD swizzle on (x,y) (nwg_xy % 8 == 0 everywhere).
// ---------------------------------------------------------------------------
template<int EPI>
__global__ __launch_bounds__(512, 1)
void gemm4r_k(const bf16* __restrict__ A, const bf16* __restrict__ Bt,
              const float* __restrict__ bias, bf16* __restrict__ outB,
              float* __restrict__ outP,
              int M, int N, int ldK, int Kchunk)
{
  __shared__ bf16 stage[6][12288];   // ring: [buf][A 128x32 (4096) | B 256x32 (8192)]

  const int tid  = threadIdx.x;
  const int wave = tid >> 6, lane = tid & 63;

  // T1 chunked XCD swizzle (x,y only; z is the K-chunk)
  const int nwg = gridDim.x * gridDim.y;
  int flat = blockIdx.y * gridDim.x + blockIdx.x;
  flat = (flat & 7) * (nwg >> 3) + (flat >> 3);
  const int bx = flat % gridDim.x, by = flat / gridDim.x;

  const int row0 = bx * 128, col0 = by * 256;
  const int wr = wave >> 2, wc = wave & 3;   // wave's 64x64 sub-tile
  const int kBase = blockIdx.z * Kchunk;

  // staging sources (3 units/wave: A rows w*16.., B rows w*16.., B rows 128+w*16..)
  const int srow = lane >> 2;                              // row within 16-chunk
  const int ssw  = ((lane & 3) ^ ((lane >> 3) & 3)) << 3;  // swizzled k elems
  const bf16* src0 = A  + (size_t)(row0 + wave * 16 + srow) * ldK + kBase + ssw;
  const bf16* src1 = Bt + (size_t)(col0 + wave * 16 + srow) * ldK + kBase + ssw;
  const bf16* src2 = Bt + (size_t)(col0 + 128 + wave * 16 + srow) * ldK + kBase + ssw;
  const int d0 = wave * 512;            // elem offsets of the 1KB units
  const int d1 = 4096 + wave * 512;
  const int d2 = 8192 + wave * 512;

  // fragment reads: slot = q ^ ((row>>1)&3); row = t*16+fr keeps it = (fr>>1)&3
  const int fr  = lane & 15;
  const int fq8 = (((lane >> 4) ^ ((fr >> 1) & 3))) << 3;

  f32x4 acc[4][4] = {};

#define STAGE6(buf, kt)                                                        \
  {                                                                            \
    const int k0_ = (kt) << 5;                                                 \
    glds16(src0 + k0_, &stage[buf][d0]);                                       \
    glds16(src1 + k0_, &stage[buf][d1]);                                       \
    glds16(src2 + k0_, &stage[buf][d2]);                                       \
  }

#define COMPUTE6(buf)                                                          \
  {                                                                            \
    const bf16* sb_ = stage[buf];                                              \
    bf16x8 af[4], bfr[4];                                                      \
    _Pragma("unroll")                                                          \
    for (int t_ = 0; t_ < 4; ++t_) {                                           \
      af[t_]  = *(const bf16x8*)&sb_[(wr * 64 + t_ * 16 + fr) * 32 + fq8];     \
      bfr[t_] = *(const bf16x8*)&sb_[4096 + (wc * 64 + t_ * 16 + fr) * 32 + fq8]; \
    }                                                                          \
    __builtin_amdgcn_s_setprio(1);                                             \
    _Pragma("unroll")                                                          \
    for (int i_ = 0; i_ < 4; ++i_)                                             \
      _Pragma("unroll")                                                        \
      for (int j_ = 0; j_ < 4; ++j_)                                           \
        acc[i_][j_] = __builtin_amdgcn_mfma_f32_16x16x32_bf16(                 \
            af[i_], bfr[j_], acc[i_][j_], 0, 0, 0);                            \
    __builtin_amdgcn_s_setprio(0);                                             \
  }

#define WAITB(n)                                                               \
  asm volatile("s_waitcnt vmcnt(" #n ")" ::: "memory");                        \
  __builtin_amdgcn_s_barrier();                                                \
  __builtin_amdgcn_sched_barrier(0);

  const int nk = Kchunk >> 5;            // 32 here (>= 6 required)
  STAGE6(0, 0); STAGE6(1, 1); STAGE6(2, 2); STAGE6(3, 3); STAGE6(4, 4);

  for (int kt = 0; kt < nk - 5; ++kt) {
    WAITB(12);                           // own stage-kt landed; 4 stages in flight
    STAGE6((kt + 5) % 6, kt + 5);
    COMPUTE6(kt % 6);
  }
  WAITB(12); COMPUTE6((nk - 5) % 6);
  WAITB(9);  COMPUTE6((nk - 4) % 6);
  WAITB(6);  COMPUTE6((nk - 3) % 6);
  WAITB(3);  COMPUTE6((nk - 2) % 6);
  WAITB(0);  COMPUTE6((nk - 1) % 6);

#undef STAGE6
#undef COMPUTE6
#undef WAITB

  // per-wave epilogue (register acc, disjoint outputs)
#pragma unroll
  for (int i = 0; i < 4; ++i) {
    const int rb = row0 + wr * 64 + i * 16 + (lane >> 4) * 4;
#pragma unroll
    for (int j = 0; j < 4; ++j) {
      const int c = col0 + wc * 64 + j * 16 + fr;
      const float bv = (EPI == 2) ? bias[c] : 0.f;
#pragma unroll
      for (int r = 0; r < 4; ++r) {
        float v = acc[i][j][r] + bv;
        if (EPI == 3) {
          outP[(size_t)blockIdx.z * M * N + (size_t)(rb + r) * N + c] = v;
        } else {
          if (EPI == 2) v = 0.5f * v * (1.f + erff(v * 0.70710678118654752f));
          outB[(size_t)(rb + r) * N + c] = (bf16)v;
        }
      }
    }
  }
}

// ---------------------------------------------------------------------------
// Split-K reduce for ff2: out = P0+P1+P2+P3 + bias + resid (fp32; out may
// alias resid). Grid = M blocks (one row each), 256 thr x f32x4 = N=1024.
// ---------------------------------------------------------------------------
__global__ __launch_bounds__(256)
void red4_k(const float* __restrict__ P, const float* __restrict__ bias,
            const float* resid, float* outF, int M, int N)
{
  const int row = blockIdx.x, c = threadIdx.x * 4;
  const size_t MN = (size_t)M * N;
  const size_t idx = (size_t)row * N + c;
  f32x4 p0 = *(const f32x4*)&P[idx];
  f32x4 p1 = *(const f32x4*)&P[MN + idx];
  f32x4 p2 = *(const f32x4*)&P[2 * MN + idx];
  f32x4 p3 = *(const f32x4*)&P[3 * MN + idx];
  f32x4 bv = *(const f32x4*)&bias[c];
  f32x4 rv = *(const f32x4*)&resid[idx];
  f32x4 o;
#pragma unroll
  for (int e = 0; e < 4; ++e) o[e] = p0[e] + p1[e] + p2[e] + p3[e] + bv[e] + rv[e];
  *(f32x4*)&outF[idx] = o;
}

// ---------------------------------------------------------------------------
// wout GEMM (N=1024, K=1024): barrier-free per-wave split-K.
// [harness-verified in round 1 -- unchanged]
// ---------------------------------------------------------------------------
__global__ __launch_bounds__(256, 2)
void gemm64s_k(const bf16* __restrict__ A, const bf16* __restrict__ Bt,
               const float* __restrict__ bias, const float* resid,
               float* outF, int M, int N, int K)
{
  union SMem {
    bf16  stage[4][2][2][2048];   // [wave][buf][A=0/B=1][64*32] = 64 KiB
    float red[4][64 * 68];        // 69632 B (padded stride 68)
  };
  __shared__ SMem sm;

  const int tid  = threadIdx.x;
  const int wave = tid >> 6, lane = tid & 63;
  const int row0 = blockIdx.x * 64, col0 = blockIdx.y * 64;
  const int kChunk = K >> 2;
  const int nk = kChunk >> 5;               // 32-wide K-steps per wave

  const int srow = lane >> 2;                              // row within 16-chunk
  const int ssw  = ((lane & 3) ^ ((lane >> 3) & 3)) << 3;  // swizzled k elems
  const bf16* Ab = A  + (size_t)(row0 + srow) * K + wave * kChunk + ssw;
  const bf16* Bb = Bt + (size_t)(col0 + srow) * K + wave * kChunk + ssw;

  const int fr  = lane & 15;
  const int fq8 = (((lane >> 4) ^ ((fr >> 1) & 3))) << 3;

  f32x4 acc[4][4] = {};

#define STAGE(buf, kt)                                                         \
  {                                                                            \
    const int k0_ = (kt) << 5;                                                 \
    bf16* pa_ = sm.stage[wave][buf][0];                                        \
    bf16* pb_ = sm.stage[wave][buf][1];                                        \
    _Pragma("unroll")                                                          \
    for (int c_ = 0; c_ < 4; ++c_) {                                           \
      glds16(Ab + (size_t)c_ * 16 * K + k0_, pa_ + c_ * 512);                  \
      glds16(Bb + (size_t)c_ * 16 * K + k0_, pb_ + c_ * 512);                  \
    }                                                                          \
  }

#define COMPUTE(buf)                                                           \
  {                                                                            \
    const bf16* pa_ = sm.stage[wave][buf][0];                                  \
    const bf16* pb_ = sm.stage[wave][buf][1];                                  \
    bf16x8 af[4], bfr[4];                                                      \
    _Pragma("unroll")                                                          \
    for (int t_ = 0; t_ < 4; ++t_) {                                           \
      af[t_]  = *(const bf16x8*)(pa_ + (t_ * 16 + fr) * 32 + fq8);             \
      bfr[t_] = *(const bf16x8*)(pb_ + (t_ * 16 + fr) * 32 + fq8);             \
    }                                                                          \
    __builtin_amdgcn_s_setprio(1);                                             \
    _Pragma("unroll")                                                          \
    for (int i_ = 0; i_ < 4; ++i_)                                             \
      _Pragma("unroll")                                                        \
      for (int j_ = 0; j_ < 4; ++j_)                                           \
        acc[i_][j_] = __builtin_amdgcn_mfma_f32_16x16x32_bf16(                 \
            af[i_], bfr[j_], acc[i_][j_], 0, 0, 0);                            \
    __builtin_amdgcn_s_setprio(0);                                             \
  }

  STAGE(0, 0);
  for (int kt = 0; kt < nk - 1; ++kt) {
    STAGE((kt + 1) & 1, kt + 1);                       // 16 outstanding
    asm volatile("s_waitcnt vmcnt(8)" ::: "memory");   // oldest 8 = cur tile
    COMPUTE(kt & 1);
  }
  asm volatile("s_waitcnt vmcnt(0)" ::: "memory");
  COMPUTE((nk - 1) & 1);

#undef STAGE
#undef COMPUTE

  // ---- cross-wave reduction (LDS reused; must fence all waves first) ----
  __syncthreads();
#pragma unroll
  for (int i = 0; i < 4; ++i)
#pragma unroll
    for (int j = 0; j < 4; ++j)
#pragma unroll
      for (int r = 0; r < 4; ++r)
        sm.red[wave][(i * 16 + ((lane >> 4) << 2) + r) * 68 + j * 16 + (lane & 15)] =
            acc[i][j][r];
  __syncthreads();

  const int er = tid >> 2;              // row 0..63
  const int ec = (tid & 3) << 2;        // col quarter-base (stride 16 via v)
  const size_t gbase = (size_t)(row0 + er) * N + col0 + ec;
#pragma unroll
  for (int v = 0; v < 4; ++v) {
    const int lo = er * 68 + ec + v * 16;
    f32x4 s0 = *(const f32x4*)&sm.red[0][lo];
    f32x4 s1 = *(const f32x4*)&sm.red[1][lo];
    f32x4 s2 = *(const f32x4*)&sm.red[2][lo];
    f32x4 s3 = *(const f32x4*)&sm.red[3][lo];
    f32x4 bv = *(const f32x4*)&bias[col0 + ec + v * 16];
    f32x4 rv = *(const f32x4*)&resid[gbase + v * 16];
    f32x4 o;
#pragma unroll
    for (int e = 0; e < 4; ++e) o[e] = s0[e] + s1[e] + s2[e] + s3[e] + bv[e] + rv[e];
    *(f32x4*)&outF[gbase + v * 16] = o;
  }
}

// ---------------------------------------------------------------------------
// Attention: qkv bf16 [B*N, 3072] -> o bf16 [B*N, 1024] (col = h*64+d)
// grid (B*H=64, N/128=4), 512 threads (8 waves, 16 q-rows each).
// ---------------------------------------------------------------------------
__global__ __launch_bounds__(512, 2)
void attn_k(const bf16* __restrict__ qkv, bf16* __restrict__ o)
{
  __shared__ bf16 Ks[512 * 72];     // [j][d], stride 72
  __shared__ bf16 Vt[64 * 520];     // [d][j], stride 520
  __shared__ bf16 Pl[8][16 * 72];   // per-wave P chunk [i][j_local], 64 cols

  const int tid = threadIdx.x, wave = tid >> 6, lane = tid & 63;
  const int b = blockIdx.x >> 4, h = blockIdx.x & 15;
  const int i0g = blockIdx.y * 128 + wave * 16;
  const bf16* base = qkv + (size_t)b * 512 * 3072;

  { // K -> LDS row-major
    const int jr = tid >> 3, c0 = (tid & 7) * 8;
#pragma unroll
    for (int p = 0; p < 8; ++p) {
      const int j = p * 64 + jr;
      *(bf16x8*)&Ks[j * 72 + c0] =
          *(const bf16x8*)&base[(size_t)j * 3072 + 1024 + h * 64 + c0];
    }
  }
  { // V -> LDS transposed
    const int jr = tid >> 4, d0 = (tid & 15) * 4;
#pragma unroll
    for (int p = 0; p < 16; ++p) {
      const int j = p * 32 + jr;
      bf16x4 v = *(const bf16x4*)&base[(size_t)j * 3072 + 2048 + h * 64 + d0];
      Vt[(d0 + 0) * 520 + j] = v[0];
      Vt[(d0 + 1) * 520 + j] = v[1];
      Vt[(d0 + 2) * 520 + j] = v[2];
      Vt[(d0 + 3) * 520 + j] = v[3];
    }
  }
  bf16x8 qf[2];
  {
    const int qr = i0g + (lane & 15);
#pragma unroll
    for (int t = 0; t < 2; ++t)
      qf[t] = *(const bf16x8*)&base[(size_t)qr * 3072 + h * 64 + t * 32 + (lane >> 4) * 8];
  }
  __syncthreads();

  // S = Q K^T : each wave 16 rows x 512 cols (32 n-tiles, 2 k-steps of 32)
  f32x4 S[32];
#pragma unroll
  for (int nt = 0; nt < 32; ++nt) {
    const bf16* kb = &Ks[(nt * 16 + (lane & 15)) * 72 + (lane >> 4) * 8];
    f32x4 c = {};
    c = __builtin_amdgcn_mfma_f32_16x16x32_bf16(qf[0], *(const bf16x8*)kb, c, 0, 0, 0);
    c = __builtin_amdgcn_mfma_f32_16x16x32_bf16(qf[1], *(const bf16x8*)(kb + 32), c, 0, 0, 0);
    S[nt] = c;
  }

  // softmax over rows (C-layout: row=(lane>>4)*4+r, col=nt*16+(lane&15))
  float mx[4] = {-1e30f, -1e30f, -1e30f, -1e30f};
#pragma unroll
  for (int nt = 0; nt < 32; ++nt)
#pragma unroll
    for (int r = 0; r < 4; ++r) {
      S[nt][r] *= 0.125f;
      mx[r] = fmaxf(mx[r], S[nt][r]);
    }
#pragma unroll
  for (int m = 1; m < 16; m <<= 1)
#pragma unroll
    for (int r = 0; r < 4; ++r) mx[r] = fmaxf(mx[r], __shfl_xor(mx[r], m));
  float sm[4] = {0.f, 0.f, 0.f, 0.f};
#pragma unroll
  for (int nt = 0; nt < 32; ++nt)
#pragma unroll
    for (int r = 0; r < 4; ++r) {
      const float e = __expf(S[nt][r] - mx[r]);
      S[nt][r] = e;
      sm[r] += e;
    }
#pragma unroll
  for (int m = 1; m < 16; m <<= 1)
#pragma unroll
    for (int r = 0; r < 4; ++r) sm[r] += __shfl_xor(sm[r], m);
  float inv[4];
#pragma unroll
  for (int r = 0; r < 4; ++r) inv[r] = 1.f / sm[r];

  // O = P V: P roundtrips per-wave LDS (C-layout -> A-layout), 8 chunks of 64
  f32x4 O[4] = {};
  for (int cch = 0; cch < 8; ++cch) {
#pragma unroll
    for (int t = 0; t < 4; ++t) {
      const int nt = cch * 4 + t;
#pragma unroll
      for (int r = 0; r < 4; ++r)
        Pl[wave][((lane >> 4) * 4 + r) * 72 + t * 16 + (lane & 15)] = (bf16)S[nt][r];
    }
#pragma unroll
    for (int ktile = 0; ktile < 2; ++ktile) {
      bf16x8 pf = *(const bf16x8*)&Pl[wave][(lane & 15) * 72 + ktile * 32 + (lane >> 4) * 8];
#pragma unroll
      for (int dt = 0; dt < 4; ++dt) {
        const bf16* vb = &Vt[(dt * 16 + (lane & 15)) * 520 + cch * 64 + ktile * 32 + (lane >> 4) * 8];
        O[dt] = __builtin_amdgcn_mfma_f32_16x16x32_bf16(pf, *(const bf16x8*)vb, O[dt], 0, 0, 0);
      }
    }
  }

#pragma unroll
  for (int dt = 0; dt < 4; ++dt)
#pragma unroll
    for (int r = 0; r < 4; ++r) {
      const int i = (lane >> 4) * 4 + r;
      const int d = dt * 16 + (lane & 15);
      o[(size_t)(b * 512 + i0g + i) * 1024 + h * 64 + d] = (bf16)(O[dt][r] * inv[r]);
    }
}

// ---------------------------------------------------------------------------
// LayerNorm: x fp32 [rows,1024], fp32 scale/bias -> bf16 out
// ---------------------------------------------------------------------------
__global__ __launch_bounds__(256)
void ln_k(const float* __restrict__ x, const float* __restrict__ sc,
          const float* __restrict__ bi, bf16* __restrict__ out)
{
  const int row = blockIdx.x, tid = threadIdx.x;
  f32x4 a = *(const f32x4*)&x[(size_t)row * 1024 + tid * 4];
  float s  = a[0] + a[1] + a[2] + a[3];
  float s2 = a[0]*a[0] + a[1]*a[1] + a[2]*a[2] + a[3]*a[3];
#pragma unroll
  for (int m = 32; m >= 1; m >>= 1) {
    s  += __shfl_xor(s, m);
    s2 += __shfl_xor(s2, m);
  }
  __shared__ float red[8];
  if ((tid & 63) == 0) { red[tid >> 6] = s; red[4 + (tid >> 6)] = s2; }
  __syncthreads();
  s  = red[0] + red[1] + red[2] + red[3];
  s2 = red[4] + red[5] + red[6] + red[7];
  const float mean = s * (1.f / 1024.f);
  const float var  = s2 * (1.f / 1024.f) - mean * mean;
  const float rs   = rsqrtf(var + 1e-5f);
  bf16x4 ov;
#pragma unroll
  for (int i = 0; i < 4; ++i) {
    const int c = tid * 4 + i;
    ov[i] = (bf16)((a[i] - mean) * rs * sc[c] + bi[c]);
  }
  *(bf16x4*)&out[(size_t)row * 1024 + tid * 4] = ov;
}

// ---------------------------------------------------------------------------
extern "C" void kernel_launch(void* const* d_in, const int* in_sizes, int n_in,
                              void* d_out, int out_size, void* d_ws, size_t ws_size,
                              hipStream_t stream)
{
  const float* x_in = (const float*)d_in[0];
  const float* ln1s = (const float*)d_in[1];
  const float* ln1b = (const float*)d_in[2];
  const float* wqkv = (const float*)d_in[3];
  const float* wout = (const float*)d_in[4];
  const float* bout = (const float*)d_in[5];
  const float* ln2s = (const float*)d_in[6];
  const float* ln2b = (const float*)d_in[7];
  const float* w1   = (const float*)d_in[8];
  const float* b1   = (const float*)d_in[9];
  const float* w2   = (const float*)d_in[10];
  const float* b2   = (const float*)d_in[11];

  char* ws = (char*)d_ws;
  const size_t MB = 1 << 20;
  float* xf   = (float*)(ws);              // 8 MiB fp32 residual stream
  bf16* act   = (bf16*)(ws + 8   * MB);    // 4 MiB: ln out / attn out
  bf16* qg    = (bf16*)(ws + 12  * MB);    // 16 MiB: qkv (12) then gelu (16)
  bf16* qkvT  = (bf16*)(ws + 28  * MB);    // 36 MiB [6][3072,1024]
  bf16* woutT = (bf16*)(ws + 64  * MB);    // 12 MiB [6][1024,1024]
  bf16* w1T   = (bf16*)(ws + 76  * MB);    // 48 MiB [6][4096,1024]
  bf16* w2T   = (bf16*)(ws + 124 * MB);    // 48 MiB [6][1024,4096]
  float* Pws  = (float*)(ws + 172 * MB);   // 32 MiB [4][2048,1024] fp32 partials

  // transpose-convert all layers' weights to bf16 [N,K]
  convT_k<<<dim3(16, 48, 6), 256, 0, stream>>>(wqkv, qkvT, 1024, 3072);
  convT_k<<<dim3(16, 16, 6), 256, 0, stream>>>(wout, woutT, 1024, 1024);
  convT_k<<<dim3(16, 64, 6), 256, 0, stream>>>(w1, w1T, 1024, 4096);
  convT_k<<<dim3(64, 16, 6), 256, 0, stream>>>(w2, w2T, 4096, 1024);

  for (int l = 0; l < 6; ++l) {
    const float* xres = (l == 0) ? x_in : xf;  // residual-stream input
    ln_k<<<2048, 256, 0, stream>>>(xres, ln1s + l * 1024, ln1b + l * 1024, act);
    gemm4r_k<0><<<dim3(16, 12, 1), 512, 0, stream>>>(
        act, qkvT + (size_t)l * 3072 * 1024, nullptr, qg, nullptr,
        2048, 3072, 1024, 1024);
    attn_k<<<dim3(64, 4), 512, 0, stream>>>(qg, act);
    gemm64s_k<<<dim3(32, 16), 256, 0, stream>>>(
        act, woutT + (size_t)l * 1024 * 1024, bout + l * 1024, xres, xf,
        2048, 1024, 1024);
    ln_k<<<2048, 256, 0, stream>>>(xf, ln2s + l * 1024, ln2b + l * 1024, act);
    gemm4r_k<2><<<dim3(16, 16, 1), 512, 0, stream>>>(
        act, w1T + (size_t)l * 4096 * 1024, b1 + l * 4096, qg, nullptr,
        2048, 4096, 1024, 1024);
    // ff2: split-K x4 on the deep-ring structure, then fused reduce
    gemm4r_k<3><<<dim3(16, 4, 4), 512, 0, stream>>>(
        qg, w2T + (size_t)l * 1024 * 4096, nullptr, nullptr, Pws,
        2048, 1024, 4096, 1024);
    float* outp = (l == 5) ? (float*)d_out : xf;
    red4_k<<<2048, 256, 0, stream>>>(Pws, b2 + l * 1024, xf, outp, 2048, 1024);
  }
}